// Round 3
// baseline (641.011 us; speedup 1.0000x reference)
//
#include <hip/hip_runtime.h>
#include <hip/hip_bf16.h>
#include <math.h>

#define BATCH   2
#define SEQ     2048
#define DM      2048
#define NH      16
#define QKR     64
#define QKN     128
#define KVL     512
#define VD      128
#define QKD     192     // QKN + QKR
#define KVA_LD  640     // padded row stride of kv_a (576 -> 640 for 128-tile GEMM)
#define RMS_EPS 1.1920928955078125e-07f

typedef __bf16 bf16x8 __attribute__((ext_vector_type(8)));
typedef float  f32x4  __attribute__((ext_vector_type(4)));

// ---- async global->LDS 16B copy (wave-uniform base + lane*16 dest semantics) ----
__device__ __forceinline__ void async16(const __bf16* g, __bf16* l)
{
    __builtin_amdgcn_global_load_lds(
        (__attribute__((address_space(1))) unsigned int*)g,
        (__attribute__((address_space(3))) unsigned int*)l,
        16, 0, 0);
}

// ---------------- fp32 [n] -> bf16 [n] ----------------
__global__ __launch_bounds__(256) void f32_to_bf16(const float* __restrict__ src,
                                                   __bf16* __restrict__ dst)
{
    int i = (blockIdx.x * 256 + threadIdx.x) * 4;
    float4 v = *reinterpret_cast<const float4*>(src + i);
    dst[i + 0] = (__bf16)v.x;
    dst[i + 1] = (__bf16)v.y;
    dst[i + 2] = (__bf16)v.z;
    dst[i + 3] = (__bf16)v.w;
}

// ---------------- W fp32 [K,N] -> W^T bf16 [Nout,K], zero-pad rows n>=N ----------------
__global__ __launch_bounds__(256) void transpose_w(const float* __restrict__ W,
                                                   __bf16* __restrict__ Wt,
                                                   int K, int N)
{
    __shared__ float t[64][65];
    const int n0 = blockIdx.x * 64, k0 = blockIdx.y * 64;
    const int tid = threadIdx.x;
    #pragma unroll
    for (int i = 0; i < 16; ++i) {
        int flat = i * 256 + tid;
        int kl = flat >> 6, nl = flat & 63;
        t[kl][nl] = (n0 + nl < N) ? W[(size_t)(k0 + kl) * N + n0 + nl] : 0.f;
    }
    __syncthreads();
    #pragma unroll
    for (int i = 0; i < 16; ++i) {
        int flat = i * 256 + tid;
        int nl = flat >> 6, kl = flat & 63;
        Wt[(size_t)(n0 + nl) * K + k0 + kl] = (__bf16)t[kl][nl];
    }
}

// ---------------- bf16 MFMA GEMM: C[M,N] = A[M,K] @ Bt[N,K]^T ----------------
template<typename OT>
__global__ __launch_bounds__(256) void gemm_bf16(const __bf16* __restrict__ A,
                                                 const __bf16* __restrict__ Bt,
                                                 OT* __restrict__ C,
                                                 int K, int lda, int ldb, int ldc)
{
    __shared__ __bf16 As[128 * 32];
    __shared__ __bf16 Bs[128 * 32];
    const int tid = threadIdx.x;
    const int lane = tid & 63, wave = tid >> 6;
    const int n = lane & 15, quad = lane >> 4;
    const int row0 = blockIdx.y * 128, col0 = blockIdx.x * 128;
    const int wm = (wave >> 1) * 64, wn = (wave & 1) * 64;

    f32x4 acc[4][4];
    #pragma unroll
    for (int mi = 0; mi < 4; ++mi)
        #pragma unroll
        for (int ni = 0; ni < 4; ++ni)
            #pragma unroll
            for (int r = 0; r < 4; ++r) acc[mi][ni][r] = 0.f;

    const __bf16* Ag0 = A  + (size_t)(row0 + (tid >> 2)) * lda + (tid & 3) * 8;
    const __bf16* Bg0 = Bt + (size_t)(col0 + (tid >> 2)) * ldb + (tid & 3) * 8;
    const __bf16* Ag1 = Ag0 + (size_t)64 * lda;
    const __bf16* Bg1 = Bg0 + (size_t)64 * ldb;
    __bf16* As0 = As + tid * 8;        __bf16* As1 = As + (tid + 256) * 8;
    __bf16* Bs0 = Bs + tid * 8;        __bf16* Bs1 = Bs + (tid + 256) * 8;

    for (int k0 = 0; k0 < K; k0 += 32) {
        __syncthreads();
        async16(Ag0 + k0, As0);
        async16(Ag1 + k0, As1);
        async16(Bg0 + k0, Bs0);
        async16(Bg1 + k0, Bs1);
        __syncthreads();

        bf16x8 af[4], bfr[4];
        #pragma unroll
        for (int mi = 0; mi < 4; ++mi)
            af[mi] = *reinterpret_cast<const bf16x8*>(&As[(wm + mi * 16 + n) * 32 + quad * 8]);
        #pragma unroll
        for (int ni = 0; ni < 4; ++ni)
            bfr[ni] = *reinterpret_cast<const bf16x8*>(&Bs[(wn + ni * 16 + n) * 32 + quad * 8]);
        #pragma unroll
        for (int mi = 0; mi < 4; ++mi)
            #pragma unroll
            for (int ni = 0; ni < 4; ++ni)
                acc[mi][ni] = __builtin_amdgcn_mfma_f32_16x16x32_bf16(af[mi], bfr[ni], acc[mi][ni], 0, 0, 0);
    }

    #pragma unroll
    for (int mi = 0; mi < 4; ++mi)
        #pragma unroll
        for (int r = 0; r < 4; ++r) {
            OT* cp = C + (size_t)(row0 + wm + mi * 16 + quad * 4 + r) * ldc + col0 + wn + n;
            #pragma unroll
            for (int ni = 0; ni < 4; ++ni)
                cp[ni * 16] = (OT)acc[mi][ni][r];
        }
}

// ---------------- RoPE on q (bf16, in-place), fp32 math ----------------
__global__ __launch_bounds__(256) void rope_q_kernel(__bf16* __restrict__ q)
{
    int idx = blockIdx.x * 256 + threadIdx.x;   // B*S*NH*32
    int i = idx & 31;
    int h = (idx >> 5) & 15;
    int s = (idx >> 9) & 2047;
    int b = idx >> 20;
    float t = (float)s * __expf(-(float)(2 * i) / 64.0f * 9.210340371976184f); // ln(10000)
    float c = __cosf(t), sn = __sinf(t);
    __bf16* p = q + ((size_t)(b * SEQ + s)) * (NH * QKD) + h * QKD + QKN + 2 * i;
    float x1 = (float)p[0], x2 = (float)p[1];
    p[0] = (__bf16)(x1 * c - x2 * sn);
    p[1] = (__bf16)(x2 * c + x1 * sn);
}

// ---------------- RoPE on k_rope: kv_a fp32 cols [512,576) -> bf16 krope [B,S,64] ----------------
__global__ __launch_bounds__(256) void rope_k_kernel(const float* __restrict__ kva,
                                                     __bf16* __restrict__ krope)
{
    int idx = blockIdx.x * 256 + threadIdx.x;   // B*S*32
    int i = idx & 31;
    int s = (idx >> 5) & 2047;
    int b = idx >> 16;
    float t = (float)s * __expf(-(float)(2 * i) / 64.0f * 9.210340371976184f);
    float c = __cosf(t), sn = __sinf(t);
    const float* p = kva + ((size_t)(b * SEQ + s)) * KVA_LD + KVL + 2 * i;
    float x1 = p[0], x2 = p[1];
    __bf16* o = krope + ((size_t)(b * SEQ + s)) * QKR + 2 * i;
    o[0] = (__bf16)(x1 * c - x2 * sn);
    o[1] = (__bf16)(x2 * c + x1 * sn);
}

// ---------------- RMSNorm c_kv (fp32 in, stride 640) -> bf16 out [4096,512] ----------------
__global__ __launch_bounds__(256) void rmsnorm_kernel(const float* __restrict__ kva,
                                                      const float* __restrict__ w,
                                                      __bf16* __restrict__ out)
{
    const int rid = blockIdx.x;
    const float* row = kva + (size_t)rid * KVA_LD;
    const int tid = threadIdx.x;
    float v[2];
    float ss = 0.f;
    #pragma unroll
    for (int j = 0; j < 2; ++j) {
        int d = tid + j * 256;
        v[j] = row[d];
        ss += v[j] * v[j];
    }
    #pragma unroll
    for (int off = 32; off > 0; off >>= 1) ss += __shfl_down(ss, off, 64);
    __shared__ float red[4];
    if ((tid & 63) == 0) red[tid >> 6] = ss;
    __syncthreads();
    float total = red[0] + red[1] + red[2] + red[3];
    float scale = 1.0f / sqrtf(total * (1.0f / KVL) + RMS_EPS);
    #pragma unroll
    for (int j = 0; j < 2; ++j) {
        int d = tid + j * 256;
        out[(size_t)rid * KVL + d] = (__bf16)(v[j] * scale * w[d]);
    }
}

// ---------------- build bf16 V^T : [B,H,128,S] from bf16 kv_b ----------------
__global__ __launch_bounds__(256) void build_vt(const __bf16* __restrict__ kvb,
                                                __bf16* __restrict__ Vt)
{
    __shared__ __bf16 tile[64][136];
    const int s0 = blockIdx.x * 64, h = blockIdx.y, b = blockIdx.z;
    const int t = threadIdx.x;
    #pragma unroll
    for (int i = 0; i < 4; ++i) {
        int flat = i * 256 + t;
        int sl = flat >> 4, c8 = flat & 15;
        bf16x8 v = *reinterpret_cast<const bf16x8*>(
            &kvb[((size_t)(b * SEQ + s0 + sl)) * (NH * 256) + h * 256 + 128 + c8 * 8]);
        *reinterpret_cast<bf16x8*>(&tile[sl][c8 * 8]) = v;
    }
    __syncthreads();
    #pragma unroll
    for (int j = 0; j < 32; ++j) {
        int flat = j * 256 + t;
        int d = flat >> 6, sl = flat & 63;
        Vt[((size_t)((b * NH + h) * VD + d)) * SEQ + s0 + sl] = tile[sl][d];
    }
}

// ---------------- MFMA flash attention, single q-strip per block ----------------
// qb: [B,S,NH*192] bf16 (rope applied); kvb: [B,S,NH*256] bf16 (k_nope|v);
// krope: [B,S,64] bf16; Vt: [B,H,128,S] bf16; ob: [B,S,NH*128] bf16
// Block = one 64-row q-strip; strip = 31 - blockIdx.x (big strips dispatch first).
// 1024 blocks, LDS 53248 B -> 3 blocks/CU capacity (vs 2 before).
#define LKS 200   // 192 + 8 pad; stride 400B -> bank windows (n+q)%8, uniform
#define LVS 72    // 64 + 8
#define LPS 72
__global__ __launch_bounds__(256, 3) void attn_mfma(const __bf16* __restrict__ qb,
                                                    const __bf16* __restrict__ kvb,
                                                    const __bf16* __restrict__ krope,
                                                    const __bf16* __restrict__ Vt,
                                                    __bf16* __restrict__ ob)
{
    __shared__ __bf16 Ks[64 * LKS];      // 25600 B
    __shared__ __bf16 Vs[128 * LVS];     // 18432 B
    __shared__ __bf16 Ps[4 * 16 * LPS];  //  9216 B   (total 53248 B)
    const int tid = threadIdx.x;
    const int wave = tid >> 6, lane = tid & 63;
    const int n = lane & 15, quad = lane >> 4;
    const int strip = 31 - blockIdx.x;       // biggest blocks first
    const int h = blockIdx.y, b = blockIdx.z;
    const int bh = b * NH + h;
    const float scale = 0.07216878364870323f;   // 1/sqrt(192)
    const int nt = strip + 1;

    // Q fragments (A-layout: m=n, k=quad*8+j)
    bf16x8 qfrag[6];
    {
        const int qrow = strip * 64 + wave * 16 + n;
        const __bf16* qp = qb + ((size_t)(b * SEQ + qrow)) * (NH * QKD) + h * QKD + quad * 8;
        #pragma unroll
        for (int c = 0; c < 6; ++c)
            qfrag[c] = *reinterpret_cast<const bf16x8*>(qp + c * 32);
    }

    f32x4 Oa[8];
    float m_i[4], l_i[4];
    #pragma unroll
    for (int i = 0; i < 8; ++i)
        #pragma unroll
        for (int r = 0; r < 4; ++r) Oa[i][r] = 0.f;
    #pragma unroll
    for (int r = 0; r < 4; ++r) { m_i[r] = -1e30f; l_i[r] = 0.f; }

    // per-thread staging coordinates
    int kkey[6], kc8[6];
    #pragma unroll
    for (int i = 0; i < 6; ++i) {
        int flat = i * 256 + tid;
        kkey[i] = flat / 24; kc8[i] = flat % 24;
    }
    const int vd = tid >> 3, vc8 = tid & 7;     // flat = i*256+tid -> d = vd + i*32

    const __bf16* Vg = Vt + (size_t)bh * VD * SEQ;

    bf16x8 kpre[6], vpre[4];
    // prefetch tile 0
    {
        const int k0 = 0;
        #pragma unroll
        for (int i = 0; i < 6; ++i) {
            const __bf16* src = (kc8[i] < 16)
                ? kvb + ((size_t)(b * SEQ + k0 + kkey[i])) * (NH * 256) + h * 256 + kc8[i] * 8
                : krope + ((size_t)(b * SEQ + k0 + kkey[i])) * QKR + (kc8[i] - 16) * 8;
            kpre[i] = *reinterpret_cast<const bf16x8*>(src);
        }
        #pragma unroll
        for (int i = 0; i < 4; ++i)
            vpre[i] = *reinterpret_cast<const bf16x8*>(Vg + (size_t)(vd + i * 32) * SEQ + k0 + vc8 * 8);
    }

    for (int kt = 0; kt < nt; ++kt) {
        __syncthreads();   // previous iteration's compute done; Ks/Vs safe to overwrite
        #pragma unroll
        for (int i = 0; i < 6; ++i)
            *reinterpret_cast<bf16x8*>(&Ks[kkey[i] * LKS + kc8[i] * 8]) = kpre[i];
        #pragma unroll
        for (int i = 0; i < 4; ++i)
            *reinterpret_cast<bf16x8*>(&Vs[(vd + i * 32) * LVS + vc8 * 8]) = vpre[i];
        __syncthreads();

        // prefetch next tile into registers (overlaps with compute below)
        if (kt + 1 < nt) {
            const int k0n = (kt + 1) * 64;
            #pragma unroll
            for (int i = 0; i < 6; ++i) {
                const __bf16* src = (kc8[i] < 16)
                    ? kvb + ((size_t)(b * SEQ + k0n + kkey[i])) * (NH * 256) + h * 256 + kc8[i] * 8
                    : krope + ((size_t)(b * SEQ + k0n + kkey[i])) * QKR + (kc8[i] - 16) * 8;
                kpre[i] = *reinterpret_cast<const bf16x8*>(src);
            }
            #pragma unroll
            for (int i = 0; i < 4; ++i)
                vpre[i] = *reinterpret_cast<const bf16x8*>(Vg + (size_t)(vd + i * 32) * SEQ + k0n + vc8 * 8);
        }

        const int k0 = kt * 64;

        // scores: S[16q x 64k], 4 key-subtiles x 6 d-chunks
        f32x4 sacc[4];
        __builtin_amdgcn_s_setprio(1);
        #pragma unroll
        for (int t = 0; t < 4; ++t) {
            f32x4 a;
            #pragma unroll
            for (int r = 0; r < 4; ++r) a[r] = 0.f;
            #pragma unroll
            for (int c = 0; c < 6; ++c) {
                bf16x8 kf = *reinterpret_cast<const bf16x8*>(&Ks[(t * 16 + n) * LKS + c * 32 + quad * 8]);
                a = __builtin_amdgcn_mfma_f32_16x16x32_bf16(qfrag[c], kf, a, 0, 0, 0);
            }
            sacc[t] = a;
        }
        __builtin_amdgcn_s_setprio(0);

        const int qg = strip * 64 + wave * 16 + quad * 4;
        const bool diag = (kt == strip);
        float mloc[4];
        #pragma unroll
        for (int r = 0; r < 4; ++r) mloc[r] = -1e30f;
        #pragma unroll
        for (int t = 0; t < 4; ++t) {
            int key = k0 + t * 16 + n;
            #pragma unroll
            for (int r = 0; r < 4; ++r) {
                float sv = sacc[t][r] * scale;
                if (diag) sv = (key <= qg + r) ? sv : -1e30f;
                sacc[t][r] = sv;
                mloc[r] = fmaxf(mloc[r], sv);
            }
        }
        #pragma unroll
        for (int off = 1; off < 16; off <<= 1)
            #pragma unroll
            for (int r = 0; r < 4; ++r)
                mloc[r] = fmaxf(mloc[r], __shfl_xor(mloc[r], off, 64));
        float alpha[4], sum[4];
        #pragma unroll
        for (int r = 0; r < 4; ++r) {
            float mn = fmaxf(m_i[r], mloc[r]);
            alpha[r] = __expf(m_i[r] - mn);
            m_i[r] = mn;
            sum[r] = 0.f;
        }
        #pragma unroll
        for (int t = 0; t < 4; ++t)
            #pragma unroll
            for (int r = 0; r < 4; ++r) {
                float p = __expf(sacc[t][r] - m_i[r]);
                sum[r] += p;
                Ps[wave * 16 * LPS + (quad * 4 + r) * LPS + t * 16 + n] = (__bf16)p;
            }
        #pragma unroll
        for (int off = 1; off < 16; off <<= 1)
            #pragma unroll
            for (int r = 0; r < 4; ++r)
                sum[r] += __shfl_xor(sum[r], off, 64);
        #pragma unroll
        for (int r = 0; r < 4; ++r) l_i[r] = l_i[r] * alpha[r] + sum[r];
        #pragma unroll
        for (int i = 0; i < 8; ++i)
            #pragma unroll
            for (int r = 0; r < 4; ++r) Oa[i][r] *= alpha[r];

        // drain P writes (per-wave region; in-wave ordering only)
        __asm__ volatile("s_waitcnt lgkmcnt(0)" ::: "memory");

        // PV: O[16q x 128vd] += P[16x64] * V[64x128]
        __builtin_amdgcn_s_setprio(1);
        #pragma unroll
        for (int kc = 0; kc < 2; ++kc) {
            bf16x8 pf = *reinterpret_cast<const bf16x8*>(&Ps[wave * 16 * LPS + n * LPS + kc * 32 + quad * 8]);
            #pragma unroll
            for (int vt = 0; vt < 8; ++vt) {
                bf16x8 vf = *reinterpret_cast<const bf16x8*>(&Vs[(vt * 16 + n) * LVS + kc * 32 + quad * 8]);
                Oa[vt] = __builtin_amdgcn_mfma_f32_16x16x32_bf16(pf, vf, Oa[vt], 0, 0, 0);
            }
        }
        __builtin_amdgcn_s_setprio(0);
    }

    // epilogue
    #pragma unroll
    for (int r = 0; r < 4; ++r) {
        float inv = 1.0f / l_i[r];
        int row = strip * 64 + wave * 16 + quad * 4 + r;
        __bf16* op = ob + ((size_t)(b * SEQ + row)) * (NH * VD) + h * VD;
        #pragma unroll
        for (int vt = 0; vt < 8; ++vt)
            op[vt * 16 + n] = (__bf16)(Oa[vt][r] * inv);
    }
}

extern "C" void kernel_launch(void* const* d_in, const int* in_sizes, int n_in,
                              void* d_out, int out_size, void* d_ws, size_t ws_size,
                              hipStream_t stream)
{
    const float* x         = (const float*)d_in[0];
    const float* Wq        = (const float*)d_in[1];
    const float* Wkv_a     = (const float*)d_in[2];
    const float* kv_norm_w = (const float*)d_in[3];
    const float* Wkv_b     = (const float*)d_in[4];
    const float* Wo        = (const float*)d_in[5];
    float* out = (float*)d_out;

    // workspace layout (f32-unit offsets); aliasing noted
    float* ws = (float*)d_ws;
    __bf16* q_bf   = (__bf16*)ws;                              // 12,582,912 bf16
    float*  kv_a   = ws + 6291456;                             // 4096x640 f32
    __bf16* kv_b   = (__bf16*)(ws + 8912896);                  // 16,777,216 bf16
    float*  r3     = ws + 17301504;                            // xb then Vt (alias)
    __bf16* xb     = (__bf16*)r3;                              // 8,388,608 bf16
    __bf16* Vt     = (__bf16*)r3;                              // 8,388,608 bf16
    float*  r4     = ws + 21495808;                            // weights then attn_o (alias)
    __bf16* Wq_t   = (__bf16*)r4;                              // 6,291,456 bf16
    __bf16* Wkva_t = (__bf16*)(r4 + 3145728);                  // 1,310,720 bf16
    __bf16* Wkvb_t = (__bf16*)(r4 + 3801088);                  // 2,097,152 bf16
    __bf16* attn_o = (__bf16*)r4;                              // 8,388,608 bf16 (weights dead)
    __bf16* Wo_t   = (__bf16*)(ws + 27787264);                 // 4,194,304 bf16
    __bf16* c_kv_n = (__bf16*)(ws + 29884416);                 // 2,097,152 bf16
    __bf16* krope  = (__bf16*)(ws + 30932992);                 //   262,144 bf16
    // total ≈ 124.3 MB

    const int M = BATCH * SEQ;   // 4096
    dim3 blk(256);

    f32_to_bf16<<<(M * DM) / 1024, blk, 0, stream>>>(x, xb);
    transpose_w<<<dim3(3072 / 64, 2048 / 64), blk, 0, stream>>>(Wq, Wq_t, DM, NH * QKD);
    transpose_w<<<dim3(640 / 64, 2048 / 64), blk, 0, stream>>>(Wkv_a, Wkva_t, DM, KVL + QKR);
    transpose_w<<<dim3(4096 / 64, 512 / 64), blk, 0, stream>>>(Wkv_b, Wkvb_t, KVL, NH * 256);
    transpose_w<<<dim3(2048 / 64, 2048 / 64), blk, 0, stream>>>(Wo, Wo_t, NH * VD, DM);

    gemm_bf16<__bf16><<<dim3(3072 / 128, M / 128), blk, 0, stream>>>(xb, Wq_t, q_bf, DM, DM, DM, NH * QKD);
    gemm_bf16<float><<<dim3(640 / 128, M / 128), blk, 0, stream>>>(xb, Wkva_t, kv_a, DM, DM, DM, KVA_LD);

    rope_q_kernel<<<(BATCH * SEQ * NH * 32) / 256, blk, 0, stream>>>(q_bf);
    rope_k_kernel<<<(BATCH * SEQ * 32) / 256, blk, 0, stream>>>(kv_a, krope);
    rmsnorm_kernel<<<M, blk, 0, stream>>>(kv_a, kv_norm_w, c_kv_n);

    gemm_bf16<__bf16><<<dim3(4096 / 128, M / 128), blk, 0, stream>>>(c_kv_n, Wkvb_t, kv_b, KVL, KVL, KVL, NH * 256);

    build_vt<<<dim3(SEQ / 64, NH, BATCH), blk, 0, stream>>>(kv_b, Vt);

    attn_mfma<<<dim3(32, NH, BATCH), blk, 0, stream>>>(q_bf, kv_b, krope, Vt, attn_o);

    gemm_bf16<float><<<dim3(2048 / 128, M / 128), blk, 0, stream>>>(attn_o, Wo_t, out, NH * VD, NH * VD, NH * VD, DM);
}

// Round 4
// 575.919 us; speedup vs baseline: 1.1130x; 1.1130x over previous
//
#include <hip/hip_runtime.h>
#include <hip/hip_bf16.h>
#include <math.h>

#define BATCH   2
#define SEQ     2048
#define DM      2048
#define NH      16
#define QKR     64
#define QKN     128
#define KVL     512
#define VD      128
#define QKD     192     // QKN + QKR
#define KVA_LD  640     // padded row stride of kv_a (576 -> 640 for 128-tile GEMM)
#define RMS_EPS 1.1920928955078125e-07f

typedef __bf16 bf16x8 __attribute__((ext_vector_type(8)));
typedef float  f32x4  __attribute__((ext_vector_type(4)));

// ---- async global->LDS 16B copy (wave-uniform base + lane*16 dest semantics) ----
__device__ __forceinline__ void async16(const __bf16* g, __bf16* l)
{
    __builtin_amdgcn_global_load_lds(
        (__attribute__((address_space(1))) unsigned int*)g,
        (__attribute__((address_space(3))) unsigned int*)l,
        16, 0, 0);
}

// ---------------- fp32 [n] -> bf16 [n] ----------------
__global__ __launch_bounds__(256) void f32_to_bf16(const float* __restrict__ src,
                                                   __bf16* __restrict__ dst)
{
    int i = (blockIdx.x * 256 + threadIdx.x) * 4;
    float4 v = *reinterpret_cast<const float4*>(src + i);
    dst[i + 0] = (__bf16)v.x;
    dst[i + 1] = (__bf16)v.y;
    dst[i + 2] = (__bf16)v.z;
    dst[i + 3] = (__bf16)v.w;
}

// ---------------- W fp32 [K,N] -> W^T bf16 [Nout,K], zero-pad rows n>=N ----------------
__global__ __launch_bounds__(256) void transpose_w(const float* __restrict__ W,
                                                   __bf16* __restrict__ Wt,
                                                   int K, int N)
{
    __shared__ float t[64][65];
    const int n0 = blockIdx.x * 64, k0 = blockIdx.y * 64;
    const int tid = threadIdx.x;
    #pragma unroll
    for (int i = 0; i < 16; ++i) {
        int flat = i * 256 + tid;
        int kl = flat >> 6, nl = flat & 63;
        t[kl][nl] = (n0 + nl < N) ? W[(size_t)(k0 + kl) * N + n0 + nl] : 0.f;
    }
    __syncthreads();
    #pragma unroll
    for (int i = 0; i < 16; ++i) {
        int flat = i * 256 + tid;
        int nl = flat >> 6, kl = flat & 63;
        Wt[(size_t)(n0 + nl) * K + k0 + kl] = (__bf16)t[kl][nl];
    }
}

// ---------------- bf16 MFMA GEMM: C[M,N] = A[M,K] @ Bt[N,K]^T ----------------
template<typename OT>
__global__ __launch_bounds__(256) void gemm_bf16(const __bf16* __restrict__ A,
                                                 const __bf16* __restrict__ Bt,
                                                 OT* __restrict__ C,
                                                 int K, int lda, int ldb, int ldc)
{
    __shared__ __bf16 As[128 * 32];
    __shared__ __bf16 Bs[128 * 32];
    const int tid = threadIdx.x;
    const int lane = tid & 63, wave = tid >> 6;
    const int n = lane & 15, quad = lane >> 4;
    const int row0 = blockIdx.y * 128, col0 = blockIdx.x * 128;
    const int wm = (wave >> 1) * 64, wn = (wave & 1) * 64;

    f32x4 acc[4][4];
    #pragma unroll
    for (int mi = 0; mi < 4; ++mi)
        #pragma unroll
        for (int ni = 0; ni < 4; ++ni)
            #pragma unroll
            for (int r = 0; r < 4; ++r) acc[mi][ni][r] = 0.f;

    const __bf16* Ag0 = A  + (size_t)(row0 + (tid >> 2)) * lda + (tid & 3) * 8;
    const __bf16* Bg0 = Bt + (size_t)(col0 + (tid >> 2)) * ldb + (tid & 3) * 8;
    const __bf16* Ag1 = Ag0 + (size_t)64 * lda;
    const __bf16* Bg1 = Bg0 + (size_t)64 * ldb;
    __bf16* As0 = As + tid * 8;        __bf16* As1 = As + (tid + 256) * 8;
    __bf16* Bs0 = Bs + tid * 8;        __bf16* Bs1 = Bs + (tid + 256) * 8;

    for (int k0 = 0; k0 < K; k0 += 32) {
        __syncthreads();
        async16(Ag0 + k0, As0);
        async16(Ag1 + k0, As1);
        async16(Bg0 + k0, Bs0);
        async16(Bg1 + k0, Bs1);
        __syncthreads();

        bf16x8 af[4], bfr[4];
        #pragma unroll
        for (int mi = 0; mi < 4; ++mi)
            af[mi] = *reinterpret_cast<const bf16x8*>(&As[(wm + mi * 16 + n) * 32 + quad * 8]);
        #pragma unroll
        for (int ni = 0; ni < 4; ++ni)
            bfr[ni] = *reinterpret_cast<const bf16x8*>(&Bs[(wn + ni * 16 + n) * 32 + quad * 8]);
        #pragma unroll
        for (int mi = 0; mi < 4; ++mi)
            #pragma unroll
            for (int ni = 0; ni < 4; ++ni)
                acc[mi][ni] = __builtin_amdgcn_mfma_f32_16x16x32_bf16(af[mi], bfr[ni], acc[mi][ni], 0, 0, 0);
    }

    #pragma unroll
    for (int mi = 0; mi < 4; ++mi)
        #pragma unroll
        for (int r = 0; r < 4; ++r) {
            OT* cp = C + (size_t)(row0 + wm + mi * 16 + quad * 4 + r) * ldc + col0 + wn + n;
            #pragma unroll
            for (int ni = 0; ni < 4; ++ni)
                cp[ni * 16] = (OT)acc[mi][ni][r];
        }
}

// ---------------- RoPE on q (bf16, in-place), fp32 math ----------------
__global__ __launch_bounds__(256) void rope_q_kernel(__bf16* __restrict__ q)
{
    int idx = blockIdx.x * 256 + threadIdx.x;   // B*S*NH*32
    int i = idx & 31;
    int h = (idx >> 5) & 15;
    int s = (idx >> 9) & 2047;
    int b = idx >> 20;
    float t = (float)s * __expf(-(float)(2 * i) / 64.0f * 9.210340371976184f); // ln(10000)
    float c = __cosf(t), sn = __sinf(t);
    __bf16* p = q + ((size_t)(b * SEQ + s)) * (NH * QKD) + h * QKD + QKN + 2 * i;
    float x1 = (float)p[0], x2 = (float)p[1];
    p[0] = (__bf16)(x1 * c - x2 * sn);
    p[1] = (__bf16)(x2 * c + x1 * sn);
}

// ---------------- RoPE on k_rope: kv_a fp32 cols [512,576) -> bf16 krope [B,S,64] ----------------
__global__ __launch_bounds__(256) void rope_k_kernel(const float* __restrict__ kva,
                                                     __bf16* __restrict__ krope)
{
    int idx = blockIdx.x * 256 + threadIdx.x;   // B*S*32
    int i = idx & 31;
    int s = (idx >> 5) & 2047;
    int b = idx >> 16;
    float t = (float)s * __expf(-(float)(2 * i) / 64.0f * 9.210340371976184f);
    float c = __cosf(t), sn = __sinf(t);
    const float* p = kva + ((size_t)(b * SEQ + s)) * KVA_LD + KVL + 2 * i;
    float x1 = p[0], x2 = p[1];
    __bf16* o = krope + ((size_t)(b * SEQ + s)) * QKR + 2 * i;
    o[0] = (__bf16)(x1 * c - x2 * sn);
    o[1] = (__bf16)(x2 * c + x1 * sn);
}

// ---------------- RMSNorm c_kv (fp32 in, stride 640) -> bf16 out [4096,512] ----------------
__global__ __launch_bounds__(256) void rmsnorm_kernel(const float* __restrict__ kva,
                                                      const float* __restrict__ w,
                                                      __bf16* __restrict__ out)
{
    const int rid = blockIdx.x;
    const float* row = kva + (size_t)rid * KVA_LD;
    const int tid = threadIdx.x;
    float v[2];
    float ss = 0.f;
    #pragma unroll
    for (int j = 0; j < 2; ++j) {
        int d = tid + j * 256;
        v[j] = row[d];
        ss += v[j] * v[j];
    }
    #pragma unroll
    for (int off = 32; off > 0; off >>= 1) ss += __shfl_down(ss, off, 64);
    __shared__ float red[4];
    if ((tid & 63) == 0) red[tid >> 6] = ss;
    __syncthreads();
    float total = red[0] + red[1] + red[2] + red[3];
    float scale = 1.0f / sqrtf(total * (1.0f / KVL) + RMS_EPS);
    #pragma unroll
    for (int j = 0; j < 2; ++j) {
        int d = tid + j * 256;
        out[(size_t)rid * KVL + d] = (__bf16)(v[j] * scale * w[d]);
    }
}

// ---------------- build bf16 V^T : [B,H,128,S] from bf16 kv_b ----------------
__global__ __launch_bounds__(256) void build_vt(const __bf16* __restrict__ kvb,
                                                __bf16* __restrict__ Vt)
{
    __shared__ __bf16 tile[64][136];
    const int s0 = blockIdx.x * 64, h = blockIdx.y, b = blockIdx.z;
    const int t = threadIdx.x;
    #pragma unroll
    for (int i = 0; i < 4; ++i) {
        int flat = i * 256 + t;
        int sl = flat >> 4, c8 = flat & 15;
        bf16x8 v = *reinterpret_cast<const bf16x8*>(
            &kvb[((size_t)(b * SEQ + s0 + sl)) * (NH * 256) + h * 256 + 128 + c8 * 8]);
        *reinterpret_cast<bf16x8*>(&tile[sl][c8 * 8]) = v;
    }
    __syncthreads();
    #pragma unroll
    for (int j = 0; j < 32; ++j) {
        int flat = j * 256 + t;
        int d = flat >> 6, sl = flat & 63;
        Vt[((size_t)((b * NH + h) * VD + d)) * SEQ + s0 + sl] = tile[sl][d];
    }
}

// ---------------- MFMA flash attention, single q-strip per block ----------------
// qb: [B,S,NH*192] bf16 (rope applied); kvb: [B,S,NH*256] bf16 (k_nope|v);
// krope: [B,S,64] bf16; Vt: [B,H,128,S] bf16; ob: [B,S,NH*128] bf16
// Block = one 64-row q-strip; strip = 31 - blockIdx.x (big strips dispatch first).
// 1024 blocks, LDS 53248 B -> 3 blocks/CU capacity.
// launch_bounds(256,2): round-0 codegen regime (128 VGPR, full prefetch overlap).
// (256,3) made the scheduler shrink to 84 VGPR by sinking prefetch loads -> 275 us. Do not use.
#define LKS 200   // 192 + 8 pad
#define LVS 72    // 64 + 8
#define LPS 72
__global__ __launch_bounds__(256, 2) void attn_mfma(const __bf16* __restrict__ qb,
                                                    const __bf16* __restrict__ kvb,
                                                    const __bf16* __restrict__ krope,
                                                    const __bf16* __restrict__ Vt,
                                                    __bf16* __restrict__ ob)
{
    __shared__ __bf16 Ks[64 * LKS];      // 25600 B
    __shared__ __bf16 Vs[128 * LVS];     // 18432 B
    __shared__ __bf16 Ps[4 * 16 * LPS];  //  9216 B   (total 53248 B)
    const int tid = threadIdx.x;
    const int wave = tid >> 6, lane = tid & 63;
    const int n = lane & 15, quad = lane >> 4;
    const int strip = 31 - blockIdx.x;       // biggest blocks first
    const int h = blockIdx.y, b = blockIdx.z;
    const int bh = b * NH + h;
    const float scale = 0.07216878364870323f;   // 1/sqrt(192)
    const int nt = strip + 1;

    // Q fragments (A-layout: m=n, k=quad*8+j)
    bf16x8 qfrag[6];
    {
        const int qrow = strip * 64 + wave * 16 + n;
        const __bf16* qp = qb + ((size_t)(b * SEQ + qrow)) * (NH * QKD) + h * QKD + quad * 8;
        #pragma unroll
        for (int c = 0; c < 6; ++c)
            qfrag[c] = *reinterpret_cast<const bf16x8*>(qp + c * 32);
    }

    f32x4 Oa[8];
    float m_i[4], l_i[4];
    #pragma unroll
    for (int i = 0; i < 8; ++i)
        #pragma unroll
        for (int r = 0; r < 4; ++r) Oa[i][r] = 0.f;
    #pragma unroll
    for (int r = 0; r < 4; ++r) { m_i[r] = -1e30f; l_i[r] = 0.f; }

    // per-thread staging coordinates
    int kkey[6], kc8[6];
    #pragma unroll
    for (int i = 0; i < 6; ++i) {
        int flat = i * 256 + tid;
        kkey[i] = flat / 24; kc8[i] = flat % 24;
    }
    const int vd = tid >> 3, vc8 = tid & 7;     // flat = i*256+tid -> d = vd + i*32

    const __bf16* Vg = Vt + (size_t)bh * VD * SEQ;

    bf16x8 kpre[6], vpre[4];
    // prefetch tile 0
    {
        const int k0 = 0;
        #pragma unroll
        for (int i = 0; i < 6; ++i) {
            const __bf16* src = (kc8[i] < 16)
                ? kvb + ((size_t)(b * SEQ + k0 + kkey[i])) * (NH * 256) + h * 256 + kc8[i] * 8
                : krope + ((size_t)(b * SEQ + k0 + kkey[i])) * QKR + (kc8[i] - 16) * 8;
            kpre[i] = *reinterpret_cast<const bf16x8*>(src);
        }
        #pragma unroll
        for (int i = 0; i < 4; ++i)
            vpre[i] = *reinterpret_cast<const bf16x8*>(Vg + (size_t)(vd + i * 32) * SEQ + k0 + vc8 * 8);
    }

    for (int kt = 0; kt < nt; ++kt) {
        __syncthreads();   // previous iteration's compute done; Ks/Vs safe to overwrite
        #pragma unroll
        for (int i = 0; i < 6; ++i)
            *reinterpret_cast<bf16x8*>(&Ks[kkey[i] * LKS + kc8[i] * 8]) = kpre[i];
        #pragma unroll
        for (int i = 0; i < 4; ++i)
            *reinterpret_cast<bf16x8*>(&Vs[(vd + i * 32) * LVS + vc8 * 8]) = vpre[i];
        __syncthreads();

        // prefetch next tile into registers (overlaps with compute below)
        if (kt + 1 < nt) {
            const int k0n = (kt + 1) * 64;
            #pragma unroll
            for (int i = 0; i < 6; ++i) {
                const __bf16* src = (kc8[i] < 16)
                    ? kvb + ((size_t)(b * SEQ + k0n + kkey[i])) * (NH * 256) + h * 256 + kc8[i] * 8
                    : krope + ((size_t)(b * SEQ + k0n + kkey[i])) * QKR + (kc8[i] - 16) * 8;
                kpre[i] = *reinterpret_cast<const bf16x8*>(src);
            }
            #pragma unroll
            for (int i = 0; i < 4; ++i)
                vpre[i] = *reinterpret_cast<const bf16x8*>(Vg + (size_t)(vd + i * 32) * SEQ + k0n + vc8 * 8);
        }
        // pin prefetch issue here: scheduler may not sink these loads below the compute
        __builtin_amdgcn_sched_barrier(0);

        const int k0 = kt * 64;

        // scores: S[16q x 64k], 4 key-subtiles x 6 d-chunks
        f32x4 sacc[4];
        __builtin_amdgcn_s_setprio(1);
        #pragma unroll
        for (int t = 0; t < 4; ++t) {
            f32x4 a;
            #pragma unroll
            for (int r = 0; r < 4; ++r) a[r] = 0.f;
            #pragma unroll
            for (int c = 0; c < 6; ++c) {
                bf16x8 kf = *reinterpret_cast<const bf16x8*>(&Ks[(t * 16 + n) * LKS + c * 32 + quad * 8]);
                a = __builtin_amdgcn_mfma_f32_16x16x32_bf16(qfrag[c], kf, a, 0, 0, 0);
            }
            sacc[t] = a;
        }
        __builtin_amdgcn_s_setprio(0);

        const int qg = strip * 64 + wave * 16 + quad * 4;
        const bool diag = (kt == strip);
        float mloc[4];
        #pragma unroll
        for (int r = 0; r < 4; ++r) mloc[r] = -1e30f;
        #pragma unroll
        for (int t = 0; t < 4; ++t) {
            int key = k0 + t * 16 + n;
            #pragma unroll
            for (int r = 0; r < 4; ++r) {
                float sv = sacc[t][r] * scale;
                if (diag) sv = (key <= qg + r) ? sv : -1e30f;
                sacc[t][r] = sv;
                mloc[r] = fmaxf(mloc[r], sv);
            }
        }
        #pragma unroll
        for (int off = 1; off < 16; off <<= 1)
            #pragma unroll
            for (int r = 0; r < 4; ++r)
                mloc[r] = fmaxf(mloc[r], __shfl_xor(mloc[r], off, 64));
        float alpha[4], sum[4];
        #pragma unroll
        for (int r = 0; r < 4; ++r) {
            float mn = fmaxf(m_i[r], mloc[r]);
            alpha[r] = __expf(m_i[r] - mn);
            m_i[r] = mn;
            sum[r] = 0.f;
        }
        #pragma unroll
        for (int t = 0; t < 4; ++t)
            #pragma unroll
            for (int r = 0; r < 4; ++r) {
                float p = __expf(sacc[t][r] - m_i[r]);
                sum[r] += p;
                Ps[wave * 16 * LPS + (quad * 4 + r) * LPS + t * 16 + n] = (__bf16)p;
            }
        #pragma unroll
        for (int off = 1; off < 16; off <<= 1)
            #pragma unroll
            for (int r = 0; r < 4; ++r)
                sum[r] += __shfl_xor(sum[r], off, 64);
        #pragma unroll
        for (int r = 0; r < 4; ++r) l_i[r] = l_i[r] * alpha[r] + sum[r];
        #pragma unroll
        for (int i = 0; i < 8; ++i)
            #pragma unroll
            for (int r = 0; r < 4; ++r) Oa[i][r] *= alpha[r];

        // drain P writes (per-wave region; in-wave ordering only)
        __asm__ volatile("s_waitcnt lgkmcnt(0)" ::: "memory");

        // PV: O[16q x 128vd] += P[16x64] * V[64x128]
        __builtin_amdgcn_s_setprio(1);
        #pragma unroll
        for (int kc = 0; kc < 2; ++kc) {
            bf16x8 pf = *reinterpret_cast<const bf16x8*>(&Ps[wave * 16 * LPS + n * LPS + kc * 32 + quad * 8]);
            #pragma unroll
            for (int vt = 0; vt < 8; ++vt) {
                bf16x8 vf = *reinterpret_cast<const bf16x8*>(&Vs[(vt * 16 + n) * LVS + kc * 32 + quad * 8]);
                Oa[vt] = __builtin_amdgcn_mfma_f32_16x16x32_bf16(pf, vf, Oa[vt], 0, 0, 0);
            }
        }
        __builtin_amdgcn_s_setprio(0);
    }

    // epilogue
    #pragma unroll
    for (int r = 0; r < 4; ++r) {
        float inv = 1.0f / l_i[r];
        int row = strip * 64 + wave * 16 + quad * 4 + r;
        __bf16* op = ob + ((size_t)(b * SEQ + row)) * (NH * VD) + h * VD;
        #pragma unroll
        for (int vt = 0; vt < 8; ++vt)
            op[vt * 16 + n] = (__bf16)(Oa[vt][r] * inv);
    }
}

extern "C" void kernel_launch(void* const* d_in, const int* in_sizes, int n_in,
                              void* d_out, int out_size, void* d_ws, size_t ws_size,
                              hipStream_t stream)
{
    const float* x         = (const float*)d_in[0];
    const float* Wq        = (const float*)d_in[1];
    const float* Wkv_a     = (const float*)d_in[2];
    const float* kv_norm_w = (const float*)d_in[3];
    const float* Wkv_b     = (const float*)d_in[4];
    const float* Wo        = (const float*)d_in[5];
    float* out = (float*)d_out;

    // workspace layout (f32-unit offsets); aliasing noted
    float* ws = (float*)d_ws;
    __bf16* q_bf   = (__bf16*)ws;                              // 12,582,912 bf16
    float*  kv_a   = ws + 6291456;                             // 4096x640 f32
    __bf16* kv_b   = (__bf16*)(ws + 8912896);                  // 16,777,216 bf16
    float*  r3     = ws + 17301504;                            // xb then Vt (alias)
    __bf16* xb     = (__bf16*)r3;                              // 8,388,608 bf16
    __bf16* Vt     = (__bf16*)r3;                              // 8,388,608 bf16
    float*  r4     = ws + 21495808;                            // weights then attn_o (alias)
    __bf16* Wq_t   = (__bf16*)r4;                              // 6,291,456 bf16
    __bf16* Wkva_t = (__bf16*)(r4 + 3145728);                  // 1,310,720 bf16
    __bf16* Wkvb_t = (__bf16*)(r4 + 3801088);                  // 2,097,152 bf16
    __bf16* attn_o = (__bf16*)r4;                              // 8,388,608 bf16 (weights dead)
    __bf16* Wo_t   = (__bf16*)(ws + 27787264);                 // 4,194,304 bf16
    __bf16* c_kv_n = (__bf16*)(ws + 29884416);                 // 2,097,152 bf16
    __bf16* krope  = (__bf16*)(ws + 30932992);                 //   262,144 bf16
    // total ≈ 124.3 MB

    const int M = BATCH * SEQ;   // 4096
    dim3 blk(256);

    f32_to_bf16<<<(M * DM) / 1024, blk, 0, stream>>>(x, xb);
    transpose_w<<<dim3(3072 / 64, 2048 / 64), blk, 0, stream>>>(Wq, Wq_t, DM, NH * QKD);
    transpose_w<<<dim3(640 / 64, 2048 / 64), blk, 0, stream>>>(Wkv_a, Wkva_t, DM, KVL + QKR);
    transpose_w<<<dim3(4096 / 64, 512 / 64), blk, 0, stream>>>(Wkv_b, Wkvb_t, KVL, NH * 256);
    transpose_w<<<dim3(2048 / 64, 2048 / 64), blk, 0, stream>>>(Wo, Wo_t, NH * VD, DM);

    gemm_bf16<__bf16><<<dim3(3072 / 128, M / 128), blk, 0, stream>>>(xb, Wq_t, q_bf, DM, DM, DM, NH * QKD);
    gemm_bf16<float><<<dim3(640 / 128, M / 128), blk, 0, stream>>>(xb, Wkva_t, kv_a, DM, DM, DM, KVA_LD);

    rope_q_kernel<<<(BATCH * SEQ * NH * 32) / 256, blk, 0, stream>>>(q_bf);
    rope_k_kernel<<<(BATCH * SEQ * 32) / 256, blk, 0, stream>>>(kv_a, krope);
    rmsnorm_kernel<<<M, blk, 0, stream>>>(kv_a, kv_norm_w, c_kv_n);

    gemm_bf16<__bf16><<<dim3(4096 / 128, M / 128), blk, 0, stream>>>(c_kv_n, Wkvb_t, kv_b, KVL, KVL, KVL, NH * 256);

    build_vt<<<dim3(SEQ / 64, NH, BATCH), blk, 0, stream>>>(kv_b, Vt);

    attn_mfma<<<dim3(32, NH, BATCH), blk, 0, stream>>>(q_bf, kv_b, krope, Vt, attn_o);

    gemm_bf16<float><<<dim3(2048 / 128, M / 128), blk, 0, stream>>>(attn_o, Wo_t, out, NH * VD, NH * VD, NH * VD, DM);
}

// Round 5
// 566.608 us; speedup vs baseline: 1.1313x; 1.0164x over previous
//
#include <hip/hip_runtime.h>
#include <hip/hip_bf16.h>
#include <math.h>

#define BATCH   2
#define SEQ     2048
#define DM      2048
#define NH      16
#define QKR     64
#define QKN     128
#define KVL     512
#define VD      128
#define QKD     192     // QKN + QKR
#define KVA_LD  640     // padded row stride of kv_a (576 -> 640 for 128-tile GEMM)
#define RMS_EPS 1.1920928955078125e-07f

typedef __bf16 bf16x8 __attribute__((ext_vector_type(8)));
typedef float  f32x4  __attribute__((ext_vector_type(4)));

// ---- async global->LDS 16B copy (wave-uniform base + lane*16 dest semantics) ----
__device__ __forceinline__ void async16(const __bf16* g, __bf16* l)
{
    __builtin_amdgcn_global_load_lds(
        (__attribute__((address_space(1))) unsigned int*)g,
        (__attribute__((address_space(3))) unsigned int*)l,
        16, 0, 0);
}

// ---------------- fp32 [n] -> bf16 [n] ----------------
__global__ __launch_bounds__(256) void f32_to_bf16(const float* __restrict__ src,
                                                   __bf16* __restrict__ dst)
{
    int i = (blockIdx.x * 256 + threadIdx.x) * 4;
    float4 v = *reinterpret_cast<const float4*>(src + i);
    dst[i + 0] = (__bf16)v.x;
    dst[i + 1] = (__bf16)v.y;
    dst[i + 2] = (__bf16)v.z;
    dst[i + 3] = (__bf16)v.w;
}

// ---------------- W fp32 [K,N] -> W^T bf16 [Nout,K], zero-pad rows n>=N ----------------
__global__ __launch_bounds__(256) void transpose_w(const float* __restrict__ W,
                                                   __bf16* __restrict__ Wt,
                                                   int K, int N)
{
    __shared__ float t[64][65];
    const int n0 = blockIdx.x * 64, k0 = blockIdx.y * 64;
    const int tid = threadIdx.x;
    #pragma unroll
    for (int i = 0; i < 16; ++i) {
        int flat = i * 256 + tid;
        int kl = flat >> 6, nl = flat & 63;
        t[kl][nl] = (n0 + nl < N) ? W[(size_t)(k0 + kl) * N + n0 + nl] : 0.f;
    }
    __syncthreads();
    #pragma unroll
    for (int i = 0; i < 16; ++i) {
        int flat = i * 256 + tid;
        int nl = flat >> 6, kl = flat & 63;
        Wt[(size_t)(n0 + nl) * K + k0 + kl] = (__bf16)t[kl][nl];
    }
}

// ---------------- bf16 MFMA GEMM: C[M,N] = A[M,K] @ Bt[N,K]^T ----------------
template<typename OT>
__global__ __launch_bounds__(256) void gemm_bf16(const __bf16* __restrict__ A,
                                                 const __bf16* __restrict__ Bt,
                                                 OT* __restrict__ C,
                                                 int K, int lda, int ldb, int ldc)
{
    __shared__ __bf16 As[128 * 32];
    __shared__ __bf16 Bs[128 * 32];
    const int tid = threadIdx.x;
    const int lane = tid & 63, wave = tid >> 6;
    const int n = lane & 15, quad = lane >> 4;
    const int row0 = blockIdx.y * 128, col0 = blockIdx.x * 128;
    const int wm = (wave >> 1) * 64, wn = (wave & 1) * 64;

    f32x4 acc[4][4];
    #pragma unroll
    for (int mi = 0; mi < 4; ++mi)
        #pragma unroll
        for (int ni = 0; ni < 4; ++ni)
            #pragma unroll
            for (int r = 0; r < 4; ++r) acc[mi][ni][r] = 0.f;

    const __bf16* Ag0 = A  + (size_t)(row0 + (tid >> 2)) * lda + (tid & 3) * 8;
    const __bf16* Bg0 = Bt + (size_t)(col0 + (tid >> 2)) * ldb + (tid & 3) * 8;
    const __bf16* Ag1 = Ag0 + (size_t)64 * lda;
    const __bf16* Bg1 = Bg0 + (size_t)64 * ldb;
    __bf16* As0 = As + tid * 8;        __bf16* As1 = As + (tid + 256) * 8;
    __bf16* Bs0 = Bs + tid * 8;        __bf16* Bs1 = Bs + (tid + 256) * 8;

    for (int k0 = 0; k0 < K; k0 += 32) {
        __syncthreads();
        async16(Ag0 + k0, As0);
        async16(Ag1 + k0, As1);
        async16(Bg0 + k0, Bs0);
        async16(Bg1 + k0, Bs1);
        __syncthreads();

        bf16x8 af[4], bfr[4];
        #pragma unroll
        for (int mi = 0; mi < 4; ++mi)
            af[mi] = *reinterpret_cast<const bf16x8*>(&As[(wm + mi * 16 + n) * 32 + quad * 8]);
        #pragma unroll
        for (int ni = 0; ni < 4; ++ni)
            bfr[ni] = *reinterpret_cast<const bf16x8*>(&Bs[(wn + ni * 16 + n) * 32 + quad * 8]);
        #pragma unroll
        for (int mi = 0; mi < 4; ++mi)
            #pragma unroll
            for (int ni = 0; ni < 4; ++ni)
                acc[mi][ni] = __builtin_amdgcn_mfma_f32_16x16x32_bf16(af[mi], bfr[ni], acc[mi][ni], 0, 0, 0);
    }

    #pragma unroll
    for (int mi = 0; mi < 4; ++mi)
        #pragma unroll
        for (int r = 0; r < 4; ++r) {
            OT* cp = C + (size_t)(row0 + wm + mi * 16 + quad * 4 + r) * ldc + col0 + wn + n;
            #pragma unroll
            for (int ni = 0; ni < 4; ++ni)
                cp[ni * 16] = (OT)acc[mi][ni][r];
        }
}

// ---------------- RoPE on q (bf16, in-place), fp32 math ----------------
__global__ __launch_bounds__(256) void rope_q_kernel(__bf16* __restrict__ q)
{
    int idx = blockIdx.x * 256 + threadIdx.x;   // B*S*NH*32
    int i = idx & 31;
    int h = (idx >> 5) & 15;
    int s = (idx >> 9) & 2047;
    int b = idx >> 20;
    float t = (float)s * __expf(-(float)(2 * i) / 64.0f * 9.210340371976184f); // ln(10000)
    float c = __cosf(t), sn = __sinf(t);
    __bf16* p = q + ((size_t)(b * SEQ + s)) * (NH * QKD) + h * QKD + QKN + 2 * i;
    float x1 = (float)p[0], x2 = (float)p[1];
    p[0] = (__bf16)(x1 * c - x2 * sn);
    p[1] = (__bf16)(x2 * c + x1 * sn);
}

// ---------------- RoPE on k_rope: kv_a fp32 cols [512,576) -> bf16 krope [B,S,64] ----------------
__global__ __launch_bounds__(256) void rope_k_kernel(const float* __restrict__ kva,
                                                     __bf16* __restrict__ krope)
{
    int idx = blockIdx.x * 256 + threadIdx.x;   // B*S*32
    int i = idx & 31;
    int s = (idx >> 5) & 2047;
    int b = idx >> 16;
    float t = (float)s * __expf(-(float)(2 * i) / 64.0f * 9.210340371976184f);
    float c = __cosf(t), sn = __sinf(t);
    const float* p = kva + ((size_t)(b * SEQ + s)) * KVA_LD + KVL + 2 * i;
    float x1 = p[0], x2 = p[1];
    __bf16* o = krope + ((size_t)(b * SEQ + s)) * QKR + 2 * i;
    o[0] = (__bf16)(x1 * c - x2 * sn);
    o[1] = (__bf16)(x2 * c + x1 * sn);
}

// ---------------- RMSNorm c_kv (fp32 in, stride 640) -> bf16 out [4096,512] ----------------
__global__ __launch_bounds__(256) void rmsnorm_kernel(const float* __restrict__ kva,
                                                      const float* __restrict__ w,
                                                      __bf16* __restrict__ out)
{
    const int rid = blockIdx.x;
    const float* row = kva + (size_t)rid * KVA_LD;
    const int tid = threadIdx.x;
    float v[2];
    float ss = 0.f;
    #pragma unroll
    for (int j = 0; j < 2; ++j) {
        int d = tid + j * 256;
        v[j] = row[d];
        ss += v[j] * v[j];
    }
    #pragma unroll
    for (int off = 32; off > 0; off >>= 1) ss += __shfl_down(ss, off, 64);
    __shared__ float red[4];
    if ((tid & 63) == 0) red[tid >> 6] = ss;
    __syncthreads();
    float total = red[0] + red[1] + red[2] + red[3];
    float scale = 1.0f / sqrtf(total * (1.0f / KVL) + RMS_EPS);
    #pragma unroll
    for (int j = 0; j < 2; ++j) {
        int d = tid + j * 256;
        out[(size_t)rid * KVL + d] = (__bf16)(v[j] * scale * w[d]);
    }
}

// ---------------- build bf16 V^T : [B,H,128,S] from bf16 kv_b ----------------
__global__ __launch_bounds__(256) void build_vt(const __bf16* __restrict__ kvb,
                                                __bf16* __restrict__ Vt)
{
    __shared__ __bf16 tile[64][136];
    const int s0 = blockIdx.x * 64, h = blockIdx.y, b = blockIdx.z;
    const int t = threadIdx.x;
    #pragma unroll
    for (int i = 0; i < 4; ++i) {
        int flat = i * 256 + t;
        int sl = flat >> 4, c8 = flat & 15;
        bf16x8 v = *reinterpret_cast<const bf16x8*>(
            &kvb[((size_t)(b * SEQ + s0 + sl)) * (NH * 256) + h * 256 + 128 + c8 * 8]);
        *reinterpret_cast<bf16x8*>(&tile[sl][c8 * 8]) = v;
    }
    __syncthreads();
    #pragma unroll
    for (int j = 0; j < 32; ++j) {
        int flat = j * 256 + t;
        int d = flat >> 6, sl = flat & 63;
        Vt[((size_t)((b * NH + h) * VD + d)) * SEQ + s0 + sl] = tile[sl][d];
    }
}

// ---------------- MFMA flash attention, paired strips x concurrent waves ----------------
// qb: [B,S,NH*192] bf16 (rope applied); kvb: [B,S,NH*256] bf16 (k_nope|v);
// krope: [B,S,64] bf16; Vt: [B,H,128,S] bf16; ob: [B,S,NH*128] bf16
// Block = pair p (512 thr, 8 waves): waves 0-3 compute strip p, waves 4-7 strip 31-p,
// CONCURRENTLY (round-0 ran the two strips serially per k-tile). K/V staging shared.
// 512 blocks x 8 waves, LDS 62464 B -> 2 blocks/CU = 16 waves/CU (round 0: 8).
// launch_bounds(512,4) caps VGPR at 128 (natural pressure ~110 after staging halved).
// History: (256,3) single-strip shrank to 84 VGPR (sunk prefetch) -> 275 us; (256,2)+pin
// single-strip -> 210 us, occ 11.5% (drain tail). Paired 4-wave r0 = 170 us. Do not split blocks.
#define LKS 200   // 192 + 8 pad
#define LVS 72    // 64 + 8
#define LPS 72
__global__ __launch_bounds__(512, 4) void attn_mfma(const __bf16* __restrict__ qb,
                                                    const __bf16* __restrict__ kvb,
                                                    const __bf16* __restrict__ krope,
                                                    const __bf16* __restrict__ Vt,
                                                    __bf16* __restrict__ ob)
{
    __shared__ __bf16 Ks[64 * LKS];      // 25600 B
    __shared__ __bf16 Vs[128 * LVS];     // 18432 B
    __shared__ __bf16 Ps[8 * 16 * LPS];  // 18432 B   (total 62464 B)
    const int tid = threadIdx.x;            // 0..511
    const int wave = tid >> 6, lane = tid & 63;
    const int n = lane & 15, quad = lane >> 4;
    const int pair = blockIdx.x, h = blockIdx.y, b = blockIdx.z;
    const int bh = b * NH + h;
    const float scale = 0.07216878364870323f;   // 1/sqrt(192)
    const int ss = wave >> 2;                   // strip side: 0 -> pair, 1 -> 31-pair
    const int ws = wave & 3;                    // wave within strip
    const int qstrip = ss ? (31 - pair) : pair;
    const int ntmax = 32 - pair;                // tiles for the long strip (pair 0 longest, dispatched first)

    // Q fragments for my wave's strip (A-layout: m=n, k=quad*8+j)
    bf16x8 qfrag[6];
    {
        const int qrow = qstrip * 64 + ws * 16 + n;
        const __bf16* qp = qb + ((size_t)(b * SEQ + qrow)) * (NH * QKD) + h * QKD + quad * 8;
        #pragma unroll
        for (int c = 0; c < 6; ++c)
            qfrag[c] = *reinterpret_cast<const bf16x8*>(qp + c * 32);
    }

    f32x4 Oa[8];
    float m_i[4], l_i[4];
    #pragma unroll
    for (int i = 0; i < 8; ++i)
        #pragma unroll
        for (int r = 0; r < 4; ++r) Oa[i][r] = 0.f;
    #pragma unroll
    for (int r = 0; r < 4; ++r) { m_i[r] = -1e30f; l_i[r] = 0.f; }

    // per-thread staging coordinates (512 threads: K = 3 chunks, V = 2 chunks each)
    int kkey[3], kc8[3];
    #pragma unroll
    for (int i = 0; i < 3; ++i) {
        int flat = i * 512 + tid;
        kkey[i] = flat / 24; kc8[i] = flat % 24;
    }
    const int vdd = tid >> 3, vc8 = tid & 7;    // d = vdd + i*64, i in {0,1}

    const __bf16* Vg = Vt + (size_t)bh * VD * SEQ;

    bf16x8 kpre[3], vpre[2];
    // prefetch tile 0
    {
        const int k0 = 0;
        #pragma unroll
        for (int i = 0; i < 3; ++i) {
            const __bf16* src = (kc8[i] < 16)
                ? kvb + ((size_t)(b * SEQ + k0 + kkey[i])) * (NH * 256) + h * 256 + kc8[i] * 8
                : krope + ((size_t)(b * SEQ + k0 + kkey[i])) * QKR + (kc8[i] - 16) * 8;
            kpre[i] = *reinterpret_cast<const bf16x8*>(src);
        }
        #pragma unroll
        for (int i = 0; i < 2; ++i)
            vpre[i] = *reinterpret_cast<const bf16x8*>(Vg + (size_t)(vdd + i * 64) * SEQ + k0 + vc8 * 8);
    }

    for (int kt = 0; kt < ntmax; ++kt) {
        __syncthreads();   // previous iteration's compute done; Ks/Vs safe to overwrite
        #pragma unroll
        for (int i = 0; i < 3; ++i)
            *reinterpret_cast<bf16x8*>(&Ks[kkey[i] * LKS + kc8[i] * 8]) = kpre[i];
        #pragma unroll
        for (int i = 0; i < 2; ++i)
            *reinterpret_cast<bf16x8*>(&Vs[(vdd + i * 64) * LVS + vc8 * 8]) = vpre[i];
        __syncthreads();

        // prefetch next tile into registers (overlaps with compute below)
        if (kt + 1 < ntmax) {
            const int k0n = (kt + 1) * 64;
            #pragma unroll
            for (int i = 0; i < 3; ++i) {
                const __bf16* src = (kc8[i] < 16)
                    ? kvb + ((size_t)(b * SEQ + k0n + kkey[i])) * (NH * 256) + h * 256 + kc8[i] * 8
                    : krope + ((size_t)(b * SEQ + k0n + kkey[i])) * QKR + (kc8[i] - 16) * 8;
                kpre[i] = *reinterpret_cast<const bf16x8*>(src);
            }
            #pragma unroll
            for (int i = 0; i < 2; ++i)
                vpre[i] = *reinterpret_cast<const bf16x8*>(Vg + (size_t)(vdd + i * 64) * SEQ + k0n + vc8 * 8);
        }
        // pin prefetch issue here: scheduler may not sink these loads below the compute
        __builtin_amdgcn_sched_barrier(0);

        if (kt <= qstrip) {     // wave-uniform: my strip still has tiles
            const int k0 = kt * 64;

            // scores: S[16q x 64k], 4 key-subtiles x 6 d-chunks
            f32x4 sacc[4];
            __builtin_amdgcn_s_setprio(1);
            #pragma unroll
            for (int t = 0; t < 4; ++t) {
                f32x4 a;
                #pragma unroll
                for (int r = 0; r < 4; ++r) a[r] = 0.f;
                #pragma unroll
                for (int c = 0; c < 6; ++c) {
                    bf16x8 kf = *reinterpret_cast<const bf16x8*>(&Ks[(t * 16 + n) * LKS + c * 32 + quad * 8]);
                    a = __builtin_amdgcn_mfma_f32_16x16x32_bf16(qfrag[c], kf, a, 0, 0, 0);
                }
                sacc[t] = a;
            }
            __builtin_amdgcn_s_setprio(0);

            const int qg = qstrip * 64 + ws * 16 + quad * 4;
            const bool diag = (kt == qstrip);
            float mloc[4];
            #pragma unroll
            for (int r = 0; r < 4; ++r) mloc[r] = -1e30f;
            #pragma unroll
            for (int t = 0; t < 4; ++t) {
                int key = k0 + t * 16 + n;
                #pragma unroll
                for (int r = 0; r < 4; ++r) {
                    float sv = sacc[t][r] * scale;
                    if (diag) sv = (key <= qg + r) ? sv : -1e30f;
                    sacc[t][r] = sv;
                    mloc[r] = fmaxf(mloc[r], sv);
                }
            }
            #pragma unroll
            for (int off = 1; off < 16; off <<= 1)
                #pragma unroll
                for (int r = 0; r < 4; ++r)
                    mloc[r] = fmaxf(mloc[r], __shfl_xor(mloc[r], off, 64));
            float alpha[4], sum[4];
            #pragma unroll
            for (int r = 0; r < 4; ++r) {
                float mn = fmaxf(m_i[r], mloc[r]);
                alpha[r] = __expf(m_i[r] - mn);
                m_i[r] = mn;
                sum[r] = 0.f;
            }
            #pragma unroll
            for (int t = 0; t < 4; ++t)
                #pragma unroll
                for (int r = 0; r < 4; ++r) {
                    float p = __expf(sacc[t][r] - m_i[r]);
                    sum[r] += p;
                    Ps[wave * 16 * LPS + (quad * 4 + r) * LPS + t * 16 + n] = (__bf16)p;
                }
            #pragma unroll
            for (int off = 1; off < 16; off <<= 1)
                #pragma unroll
                for (int r = 0; r < 4; ++r)
                    sum[r] += __shfl_xor(sum[r], off, 64);
            #pragma unroll
            for (int r = 0; r < 4; ++r) l_i[r] = l_i[r] * alpha[r] + sum[r];
            #pragma unroll
            for (int i = 0; i < 8; ++i)
                #pragma unroll
                for (int r = 0; r < 4; ++r) Oa[i][r] *= alpha[r];

            // drain P writes (per-wave region; in-wave ordering only)
            __asm__ volatile("s_waitcnt lgkmcnt(0)" ::: "memory");

            // PV: O[16q x 128vd] += P[16x64] * V[64x128]
            __builtin_amdgcn_s_setprio(1);
            #pragma unroll
            for (int kc = 0; kc < 2; ++kc) {
                bf16x8 pf = *reinterpret_cast<const bf16x8*>(&Ps[wave * 16 * LPS + n * LPS + kc * 32 + quad * 8]);
                #pragma unroll
                for (int vt = 0; vt < 8; ++vt) {
                    bf16x8 vf = *reinterpret_cast<const bf16x8*>(&Vs[(vt * 16 + n) * LVS + kc * 32 + quad * 8]);
                    Oa[vt] = __builtin_amdgcn_mfma_f32_16x16x32_bf16(pf, vf, Oa[vt], 0, 0, 0);
                }
            }
            __builtin_amdgcn_s_setprio(0);
        }
    }

    // epilogue
    #pragma unroll
    for (int r = 0; r < 4; ++r) {
        float inv = 1.0f / l_i[r];
        int row = qstrip * 64 + ws * 16 + quad * 4 + r;
        __bf16* op = ob + ((size_t)(b * SEQ + row)) * (NH * VD) + h * VD;
        #pragma unroll
        for (int vt = 0; vt < 8; ++vt)
            op[vt * 16 + n] = (__bf16)(Oa[vt][r] * inv);
    }
}

extern "C" void kernel_launch(void* const* d_in, const int* in_sizes, int n_in,
                              void* d_out, int out_size, void* d_ws, size_t ws_size,
                              hipStream_t stream)
{
    const float* x         = (const float*)d_in[0];
    const float* Wq        = (const float*)d_in[1];
    const float* Wkv_a     = (const float*)d_in[2];
    const float* kv_norm_w = (const float*)d_in[3];
    const float* Wkv_b     = (const float*)d_in[4];
    const float* Wo        = (const float*)d_in[5];
    float* out = (float*)d_out;

    // workspace layout (f32-unit offsets); aliasing noted
    float* ws = (float*)d_ws;
    __bf16* q_bf   = (__bf16*)ws;                              // 12,582,912 bf16
    float*  kv_a   = ws + 6291456;                             // 4096x640 f32
    __bf16* kv_b   = (__bf16*)(ws + 8912896);                  // 16,777,216 bf16
    float*  r3     = ws + 17301504;                            // xb then Vt (alias)
    __bf16* xb     = (__bf16*)r3;                              // 8,388,608 bf16
    __bf16* Vt     = (__bf16*)r3;                              // 8,388,608 bf16
    float*  r4     = ws + 21495808;                            // weights then attn_o (alias)
    __bf16* Wq_t   = (__bf16*)r4;                              // 6,291,456 bf16
    __bf16* Wkva_t = (__bf16*)(r4 + 3145728);                  // 1,310,720 bf16
    __bf16* Wkvb_t = (__bf16*)(r4 + 3801088);                  // 2,097,152 bf16
    __bf16* attn_o = (__bf16*)r4;                              // 8,388,608 bf16 (weights dead)
    __bf16* Wo_t   = (__bf16*)(ws + 27787264);                 // 4,194,304 bf16
    __bf16* c_kv_n = (__bf16*)(ws + 29884416);                 // 2,097,152 bf16
    __bf16* krope  = (__bf16*)(ws + 30932992);                 //   262,144 bf16
    // total ≈ 124.3 MB

    const int M = BATCH * SEQ;   // 4096
    dim3 blk(256);

    f32_to_bf16<<<(M * DM) / 1024, blk, 0, stream>>>(x, xb);
    transpose_w<<<dim3(3072 / 64, 2048 / 64), blk, 0, stream>>>(Wq, Wq_t, DM, NH * QKD);
    transpose_w<<<dim3(640 / 64, 2048 / 64), blk, 0, stream>>>(Wkv_a, Wkva_t, DM, KVL + QKR);
    transpose_w<<<dim3(4096 / 64, 512 / 64), blk, 0, stream>>>(Wkv_b, Wkvb_t, KVL, NH * 256);
    transpose_w<<<dim3(2048 / 64, 2048 / 64), blk, 0, stream>>>(Wo, Wo_t, NH * VD, DM);

    gemm_bf16<__bf16><<<dim3(3072 / 128, M / 128), blk, 0, stream>>>(xb, Wq_t, q_bf, DM, DM, DM, NH * QKD);
    gemm_bf16<float><<<dim3(640 / 128, M / 128), blk, 0, stream>>>(xb, Wkva_t, kv_a, DM, DM, DM, KVA_LD);

    rope_q_kernel<<<(BATCH * SEQ * NH * 32) / 256, blk, 0, stream>>>(q_bf);
    rope_k_kernel<<<(BATCH * SEQ * 32) / 256, blk, 0, stream>>>(kv_a, krope);
    rmsnorm_kernel<<<M, blk, 0, stream>>>(kv_a, kv_norm_w, c_kv_n);

    gemm_bf16<__bf16><<<dim3(4096 / 128, M / 128), blk, 0, stream>>>(c_kv_n, Wkvb_t, kv_b, KVL, KVL, KVL, NH * 256);

    build_vt<<<dim3(SEQ / 64, NH, BATCH), blk, 0, stream>>>(kv_b, Vt);

    attn_mfma<<<dim3(16, NH, BATCH), dim3(512), 0, stream>>>(q_bf, kv_b, krope, Vt, attn_o);

    gemm_bf16<float><<<dim3(2048 / 128, M / 128), blk, 0, stream>>>(attn_o, Wo_t, out, NH * VD, NH * VD, NH * VD, DM);
}

// Round 6
// 506.910 us; speedup vs baseline: 1.2645x; 1.1178x over previous
//
#include <hip/hip_runtime.h>
#include <hip/hip_bf16.h>
#include <math.h>

#define BATCH   2
#define SEQ     2048
#define DM      2048
#define NH      16
#define QKR     64
#define QKN     128
#define KVL     512
#define VD      128
#define QKD     192     // QKN + QKR
#define KVA_LD  640     // padded row stride of kv_a (576 -> 640 for 128-tile GEMM)
#define RMS_EPS 1.1920928955078125e-07f

typedef __bf16 bf16x8 __attribute__((ext_vector_type(8)));
typedef float  f32x4  __attribute__((ext_vector_type(4)));

// ---- async global->LDS 16B copy (wave-uniform base + lane*16 dest semantics) ----
__device__ __forceinline__ void async16(const __bf16* g, __bf16* l)
{
    __builtin_amdgcn_global_load_lds(
        (__attribute__((address_space(1))) unsigned int*)g,
        (__attribute__((address_space(3))) unsigned int*)l,
        16, 0, 0);
}

// ---------------- fp32 [n] -> bf16 [n] ----------------
__global__ __launch_bounds__(256) void f32_to_bf16(const float* __restrict__ src,
                                                   __bf16* __restrict__ dst)
{
    int i = (blockIdx.x * 256 + threadIdx.x) * 4;
    float4 v = *reinterpret_cast<const float4*>(src + i);
    dst[i + 0] = (__bf16)v.x;
    dst[i + 1] = (__bf16)v.y;
    dst[i + 2] = (__bf16)v.z;
    dst[i + 3] = (__bf16)v.w;
}

// ---------------- W fp32 [K,N] -> W^T bf16 [Nout,K], zero-pad rows n>=N ----------------
__global__ __launch_bounds__(256) void transpose_w(const float* __restrict__ W,
                                                   __bf16* __restrict__ Wt,
                                                   int K, int N)
{
    __shared__ float t[64][65];
    const int n0 = blockIdx.x * 64, k0 = blockIdx.y * 64;
    const int tid = threadIdx.x;
    #pragma unroll
    for (int i = 0; i < 16; ++i) {
        int flat = i * 256 + tid;
        int kl = flat >> 6, nl = flat & 63;
        t[kl][nl] = (n0 + nl < N) ? W[(size_t)(k0 + kl) * N + n0 + nl] : 0.f;
    }
    __syncthreads();
    #pragma unroll
    for (int i = 0; i < 16; ++i) {
        int flat = i * 256 + tid;
        int nl = flat >> 6, kl = flat & 63;
        Wt[(size_t)(n0 + nl) * K + k0 + kl] = (__bf16)t[kl][nl];
    }
}

// ---------------- bf16 MFMA GEMM: C[M,N] = A[M,K] @ Bt[N,K]^T ----------------
// BK=64 (2 k-chunks of 32 per stage): halves barrier count vs BK=32.
// LDS [128][64] row stride = 128B = exact 32-bank wrap -> 16B-slot XOR swizzle
// (col8 ^ (row&7)) applied on BOTH the global source (async16 dest is linear)
// and the ds_read slot (rule: both-sides-or-neither). 2 lanes/bank after swizzle.
template<typename OT>
__global__ __launch_bounds__(256) void gemm_bf16(const __bf16* __restrict__ A,
                                                 const __bf16* __restrict__ Bt,
                                                 OT* __restrict__ C,
                                                 int K, int lda, int ldb, int ldc)
{
    __shared__ __bf16 As[128 * 64];
    __shared__ __bf16 Bs[128 * 64];
    const int tid = threadIdx.x;
    const int lane = tid & 63, wave = tid >> 6;
    const int n = lane & 15, quad = lane >> 4;
    const int row0 = blockIdx.y * 128, col0 = blockIdx.x * 128;
    const int wm = (wave >> 1) * 64, wn = (wave & 1) * 64;

    f32x4 acc[4][4];
    #pragma unroll
    for (int mi = 0; mi < 4; ++mi)
        #pragma unroll
        for (int ni = 0; ni < 4; ++ni)
            #pragma unroll
            for (int r = 0; r < 4; ++r) acc[mi][ni][r] = 0.f;

    // staging coords: per call i (4 calls/matrix): flat = i*256+tid,
    // row = flat>>3 (+32 per call), phys col8 slot = flat&7,
    // logical col8 = phys ^ (row&7)  (inverse-swizzled source)
    const int srow = tid >> 3;
    const int scol8p = tid & 7;
    const __bf16* Ag[4]; const __bf16* Bg[4];
    #pragma unroll
    for (int i = 0; i < 4; ++i) {
        int row = srow + i * 32;
        int col8l = scol8p ^ (row & 7);
        Ag[i] = A  + (size_t)(row0 + row) * lda + col8l * 8;
        Bg[i] = Bt + (size_t)(col0 + row) * ldb + col8l * 8;
    }
    __bf16* Asd = As + tid * 8;   // + i*2048 elements per call (4KB)
    __bf16* Bsd = Bs + tid * 8;

    for (int k0 = 0; k0 < K; k0 += 64) {
        __syncthreads();
        #pragma unroll
        for (int i = 0; i < 4; ++i) {
            async16(Ag[i] + k0, Asd + i * 2048);
            async16(Bg[i] + k0, Bsd + i * 2048);
        }
        __syncthreads();

        #pragma unroll
        for (int kc = 0; kc < 2; ++kc) {
            bf16x8 af[4], bfr[4];
            #pragma unroll
            for (int mi = 0; mi < 4; ++mi) {
                int row = wm + mi * 16 + n;
                int slot = (kc * 4 + quad) ^ (row & 7);
                af[mi] = *reinterpret_cast<const bf16x8*>(&As[row * 64 + slot * 8]);
            }
            #pragma unroll
            for (int ni = 0; ni < 4; ++ni) {
                int row = wn + ni * 16 + n;
                int slot = (kc * 4 + quad) ^ (row & 7);
                bfr[ni] = *reinterpret_cast<const bf16x8*>(&Bs[row * 64 + slot * 8]);
            }
            #pragma unroll
            for (int mi = 0; mi < 4; ++mi)
                #pragma unroll
                for (int ni = 0; ni < 4; ++ni)
                    acc[mi][ni] = __builtin_amdgcn_mfma_f32_16x16x32_bf16(af[mi], bfr[ni], acc[mi][ni], 0, 0, 0);
        }
    }

    #pragma unroll
    for (int mi = 0; mi < 4; ++mi)
        #pragma unroll
        for (int r = 0; r < 4; ++r) {
            OT* cp = C + (size_t)(row0 + wm + mi * 16 + quad * 4 + r) * ldc + col0 + wn + n;
            #pragma unroll
            for (int ni = 0; ni < 4; ++ni)
                cp[ni * 16] = (OT)acc[mi][ni][r];
        }
}

// ---------------- RoPE on q (bf16, in-place), fp32 math ----------------
__global__ __launch_bounds__(256) void rope_q_kernel(__bf16* __restrict__ q)
{
    int idx = blockIdx.x * 256 + threadIdx.x;   // B*S*NH*32
    int i = idx & 31;
    int h = (idx >> 5) & 15;
    int s = (idx >> 9) & 2047;
    int b = idx >> 20;
    float t = (float)s * __expf(-(float)(2 * i) / 64.0f * 9.210340371976184f); // ln(10000)
    float c = __cosf(t), sn = __sinf(t);
    __bf16* p = q + ((size_t)(b * SEQ + s)) * (NH * QKD) + h * QKD + QKN + 2 * i;
    float x1 = (float)p[0], x2 = (float)p[1];
    p[0] = (__bf16)(x1 * c - x2 * sn);
    p[1] = (__bf16)(x2 * c + x1 * sn);
}

// ---------------- RoPE on k_rope: kv_a fp32 cols [512,576) -> bf16 krope [B,S,64] ----------------
__global__ __launch_bounds__(256) void rope_k_kernel(const float* __restrict__ kva,
                                                     __bf16* __restrict__ krope)
{
    int idx = blockIdx.x * 256 + threadIdx.x;   // B*S*32
    int i = idx & 31;
    int s = (idx >> 5) & 2047;
    int b = idx >> 16;
    float t = (float)s * __expf(-(float)(2 * i) / 64.0f * 9.210340371976184f);
    float c = __cosf(t), sn = __sinf(t);
    const float* p = kva + ((size_t)(b * SEQ + s)) * KVA_LD + KVL + 2 * i;
    float x1 = p[0], x2 = p[1];
    __bf16* o = krope + ((size_t)(b * SEQ + s)) * QKR + 2 * i;
    o[0] = (__bf16)(x1 * c - x2 * sn);
    o[1] = (__bf16)(x2 * c + x1 * sn);
}

// ---------------- RMSNorm c_kv (fp32 in, stride 640) -> bf16 out [4096,512] ----------------
__global__ __launch_bounds__(256) void rmsnorm_kernel(const float* __restrict__ kva,
                                                      const float* __restrict__ w,
                                                      __bf16* __restrict__ out)
{
    const int rid = blockIdx.x;
    const float* row = kva + (size_t)rid * KVA_LD;
    const int tid = threadIdx.x;
    float v[2];
    float ss = 0.f;
    #pragma unroll
    for (int j = 0; j < 2; ++j) {
        int d = tid + j * 256;
        v[j] = row[d];
        ss += v[j] * v[j];
    }
    #pragma unroll
    for (int off = 32; off > 0; off >>= 1) ss += __shfl_down(ss, off, 64);
    __shared__ float red[4];
    if ((tid & 63) == 0) red[tid >> 6] = ss;
    __syncthreads();
    float total = red[0] + red[1] + red[2] + red[3];
    float scale = 1.0f / sqrtf(total * (1.0f / KVL) + RMS_EPS);
    #pragma unroll
    for (int j = 0; j < 2; ++j) {
        int d = tid + j * 256;
        out[(size_t)rid * KVL + d] = (__bf16)(v[j] * scale * w[d]);
    }
}

// ---------------- build bf16 V^T : [B,H,128,S] from bf16 kv_b ----------------
__global__ __launch_bounds__(256) void build_vt(const __bf16* __restrict__ kvb,
                                                __bf16* __restrict__ Vt)
{
    __shared__ __bf16 tile[64][136];
    const int s0 = blockIdx.x * 64, h = blockIdx.y, b = blockIdx.z;
    const int t = threadIdx.x;
    #pragma unroll
    for (int i = 0; i < 4; ++i) {
        int flat = i * 256 + t;
        int sl = flat >> 4, c8 = flat & 15;
        bf16x8 v = *reinterpret_cast<const bf16x8*>(
            &kvb[((size_t)(b * SEQ + s0 + sl)) * (NH * 256) + h * 256 + 128 + c8 * 8]);
        *reinterpret_cast<bf16x8*>(&tile[sl][c8 * 8]) = v;
    }
    __syncthreads();
    #pragma unroll
    for (int j = 0; j < 32; ++j) {
        int flat = j * 256 + t;
        int d = flat >> 6, sl = flat & 63;
        Vt[((size_t)((b * NH + h) * VD + d)) * SEQ + s0 + sl] = tile[sl][d];
    }
}

// ---------------- MFMA flash attention, paired q-strips (round-0 exact) ----------------
// qb: [B,S,NH*192] bf16 (rope applied); kvb: [B,S,NH*256] bf16 (k_nope|v);
// krope: [B,S,64] bf16; Vt: [B,H,128,S] bf16; ob: [B,S,NH*128] bf16
// Block = pair p: strips qs0=p (k-tiles 0..p) and qs1=31-p (k-tiles 0..31-p), SERIAL
// per k-tile (2 strips x 80 MFMA between barrier pairs = best stage amortization).
// History: single-strip (256,3)=275us (VGPR 84), (256,2)+pin=210us (drain tail),
// 8-wave concurrent strips (512,4)=200us (VGPR 64, prefetch sunk). This = 170us. Keep.
#define LKS 216   // 192 + 24 pad
#define LVS 72    // 64 + 8
#define LPS 72
__global__ __launch_bounds__(256, 2) void attn_mfma(const __bf16* __restrict__ qb,
                                                    const __bf16* __restrict__ kvb,
                                                    const __bf16* __restrict__ krope,
                                                    const __bf16* __restrict__ Vt,
                                                    __bf16* __restrict__ ob)
{
    __shared__ __bf16 Ks[64 * LKS];        // 27648 B
    __shared__ __bf16 Vs[128 * LVS];       // 18432 B
    __shared__ __bf16 Ps[2][4 * 16 * LPS]; // 18432 B   (total 64512 B)
    const int tid = threadIdx.x;
    const int wave = tid >> 6, lane = tid & 63;
    const int n = lane & 15, quad = lane >> 4;
    const int pair = blockIdx.x, h = blockIdx.y, b = blockIdx.z;
    const int bh = b * NH + h;
    const float scale = 0.07216878364870323f;   // 1/sqrt(192)
    int qs[2];
    qs[0] = pair; qs[1] = 31 - pair;
    const int ntmax = qs[1] + 1;

    // Q fragments for both strips (A-layout: m=n, k=quad*8+j)
    bf16x8 qfrag[2][6];
    #pragma unroll
    for (int s = 0; s < 2; ++s) {
        const int qrow = qs[s] * 64 + wave * 16 + n;
        const __bf16* qp = qb + ((size_t)(b * SEQ + qrow)) * (NH * QKD) + h * QKD + quad * 8;
        #pragma unroll
        for (int c = 0; c < 6; ++c)
            qfrag[s][c] = *reinterpret_cast<const bf16x8*>(qp + c * 32);
    }

    f32x4 Oa[2][8];
    float m_i[2][4], l_i[2][4];
    #pragma unroll
    for (int s = 0; s < 2; ++s) {
        #pragma unroll
        for (int i = 0; i < 8; ++i)
            #pragma unroll
            for (int r = 0; r < 4; ++r) Oa[s][i][r] = 0.f;
        #pragma unroll
        for (int r = 0; r < 4; ++r) { m_i[s][r] = -1e30f; l_i[s][r] = 0.f; }
    }

    // per-thread staging coordinates
    int kkey[6], kc8[6];
    #pragma unroll
    for (int i = 0; i < 6; ++i) {
        int flat = i * 256 + tid;
        kkey[i] = flat / 24; kc8[i] = flat % 24;
    }
    const int vd = tid >> 3, vc8 = tid & 7;     // flat = i*256+tid -> d = vd + i*32

    const __bf16* Vg = Vt + (size_t)bh * VD * SEQ;

    bf16x8 kpre[6], vpre[4];
    // prefetch tile 0
    {
        const int k0 = 0;
        #pragma unroll
        for (int i = 0; i < 6; ++i) {
            const __bf16* src = (kc8[i] < 16)
                ? kvb + ((size_t)(b * SEQ + k0 + kkey[i])) * (NH * 256) + h * 256 + kc8[i] * 8
                : krope + ((size_t)(b * SEQ + k0 + kkey[i])) * QKR + (kc8[i] - 16) * 8;
            kpre[i] = *reinterpret_cast<const bf16x8*>(src);
        }
        #pragma unroll
        for (int i = 0; i < 4; ++i)
            vpre[i] = *reinterpret_cast<const bf16x8*>(Vg + (size_t)(vd + i * 32) * SEQ + k0 + vc8 * 8);
    }

    for (int kt = 0; kt < ntmax; ++kt) {
        __syncthreads();   // previous iteration's compute done; Ks/Vs safe to overwrite
        #pragma unroll
        for (int i = 0; i < 6; ++i)
            *reinterpret_cast<bf16x8*>(&Ks[kkey[i] * LKS + kc8[i] * 8]) = kpre[i];
        #pragma unroll
        for (int i = 0; i < 4; ++i)
            *reinterpret_cast<bf16x8*>(&Vs[(vd + i * 32) * LVS + vc8 * 8]) = vpre[i];
        __syncthreads();

        // prefetch next tile into registers (overlaps with compute below)
        if (kt + 1 < ntmax) {
            const int k0n = (kt + 1) * 64;
            #pragma unroll
            for (int i = 0; i < 6; ++i) {
                const __bf16* src = (kc8[i] < 16)
                    ? kvb + ((size_t)(b * SEQ + k0n + kkey[i])) * (NH * 256) + h * 256 + kc8[i] * 8
                    : krope + ((size_t)(b * SEQ + k0n + kkey[i])) * QKR + (kc8[i] - 16) * 8;
                kpre[i] = *reinterpret_cast<const bf16x8*>(src);
            }
            #pragma unroll
            for (int i = 0; i < 4; ++i)
                vpre[i] = *reinterpret_cast<const bf16x8*>(Vg + (size_t)(vd + i * 32) * SEQ + k0n + vc8 * 8);
        }

        const int k0 = kt * 64;
        #pragma unroll
        for (int s = 0; s < 2; ++s) {
            if (kt > qs[s]) continue;      // strip 0 done after its diagonal

            // scores: S[16q x 64k], 4 key-subtiles x 6 d-chunks
            f32x4 sacc[4];
            #pragma unroll
            for (int t = 0; t < 4; ++t) {
                f32x4 a;
                #pragma unroll
                for (int r = 0; r < 4; ++r) a[r] = 0.f;
                #pragma unroll
                for (int c = 0; c < 6; ++c) {
                    bf16x8 kf = *reinterpret_cast<const bf16x8*>(&Ks[(t * 16 + n) * LKS + c * 32 + quad * 8]);
                    a = __builtin_amdgcn_mfma_f32_16x16x32_bf16(qfrag[s][c], kf, a, 0, 0, 0);
                }
                sacc[t] = a;
            }

            const int qg = qs[s] * 64 + wave * 16 + quad * 4;
            const bool diag = (kt == qs[s]);
            float mloc[4];
            #pragma unroll
            for (int r = 0; r < 4; ++r) mloc[r] = -1e30f;
            #pragma unroll
            for (int t = 0; t < 4; ++t) {
                int key = k0 + t * 16 + n;
                #pragma unroll
                for (int r = 0; r < 4; ++r) {
                    float sv = sacc[t][r] * scale;
                    if (diag) sv = (key <= qg + r) ? sv : -1e30f;
                    sacc[t][r] = sv;
                    mloc[r] = fmaxf(mloc[r], sv);
                }
            }
            #pragma unroll
            for (int off = 1; off < 16; off <<= 1)
                #pragma unroll
                for (int r = 0; r < 4; ++r)
                    mloc[r] = fmaxf(mloc[r], __shfl_xor(mloc[r], off, 64));
            float alpha[4], sum[4];
            #pragma unroll
            for (int r = 0; r < 4; ++r) {
                float mn = fmaxf(m_i[s][r], mloc[r]);
                alpha[r] = __expf(m_i[s][r] - mn);
                m_i[s][r] = mn;
                sum[r] = 0.f;
            }
            #pragma unroll
            for (int t = 0; t < 4; ++t)
                #pragma unroll
                for (int r = 0; r < 4; ++r) {
                    float p = __expf(sacc[t][r] - m_i[s][r]);
                    sum[r] += p;
                    Ps[s][wave * 16 * LPS + (quad * 4 + r) * LPS + t * 16 + n] = (__bf16)p;
                }
            #pragma unroll
            for (int off = 1; off < 16; off <<= 1)
                #pragma unroll
                for (int r = 0; r < 4; ++r)
                    sum[r] += __shfl_xor(sum[r], off, 64);
            #pragma unroll
            for (int r = 0; r < 4; ++r) l_i[s][r] = l_i[s][r] * alpha[r] + sum[r];
            #pragma unroll
            for (int i = 0; i < 8; ++i)
                #pragma unroll
                for (int r = 0; r < 4; ++r) Oa[s][i][r] *= alpha[r];

            // drain P writes (per-wave region; in-wave ordering only)
            __asm__ volatile("s_waitcnt lgkmcnt(0)" ::: "memory");

            // PV: O[16q x 128vd] += P[16x64] * V[64x128]
            #pragma unroll
            for (int kc = 0; kc < 2; ++kc) {
                bf16x8 pf = *reinterpret_cast<const bf16x8*>(&Ps[s][wave * 16 * LPS + n * LPS + kc * 32 + quad * 8]);
                #pragma unroll
                for (int vt = 0; vt < 8; ++vt) {
                    bf16x8 vf = *reinterpret_cast<const bf16x8*>(&Vs[(vt * 16 + n) * LVS + kc * 32 + quad * 8]);
                    Oa[s][vt] = __builtin_amdgcn_mfma_f32_16x16x32_bf16(pf, vf, Oa[s][vt], 0, 0, 0);
                }
            }
        }
    }

    // epilogue: both strips
    #pragma unroll
    for (int s = 0; s < 2; ++s)
        #pragma unroll
        for (int r = 0; r < 4; ++r) {
            float inv = 1.0f / l_i[s][r];
            int row = qs[s] * 64 + wave * 16 + quad * 4 + r;
            __bf16* op = ob + ((size_t)(b * SEQ + row)) * (NH * VD) + h * VD;
            #pragma unroll
            for (int vt = 0; vt < 8; ++vt)
                op[vt * 16 + n] = (__bf16)(Oa[s][vt][r] * inv);
        }
}

extern "C" void kernel_launch(void* const* d_in, const int* in_sizes, int n_in,
                              void* d_out, int out_size, void* d_ws, size_t ws_size,
                              hipStream_t stream)
{
    const float* x         = (const float*)d_in[0];
    const float* Wq        = (const float*)d_in[1];
    const float* Wkv_a     = (const float*)d_in[2];
    const float* kv_norm_w = (const float*)d_in[3];
    const float* Wkv_b     = (const float*)d_in[4];
    const float* Wo        = (const float*)d_in[5];
    float* out = (float*)d_out;

    // workspace layout (f32-unit offsets); aliasing noted
    float* ws = (float*)d_ws;
    __bf16* q_bf   = (__bf16*)ws;                              // 12,582,912 bf16
    float*  kv_a   = ws + 6291456;                             // 4096x640 f32
    __bf16* kv_b   = (__bf16*)(ws + 8912896);                  // 16,777,216 bf16
    float*  r3     = ws + 17301504;                            // xb then Vt (alias)
    __bf16* xb     = (__bf16*)r3;                              // 8,388,608 bf16
    __bf16* Vt     = (__bf16*)r3;                              // 8,388,608 bf16
    float*  r4     = ws + 21495808;                            // weights then attn_o (alias)
    __bf16* Wq_t   = (__bf16*)r4;                              // 6,291,456 bf16
    __bf16* Wkva_t = (__bf16*)(r4 + 3145728);                  // 1,310,720 bf16
    __bf16* Wkvb_t = (__bf16*)(r4 + 3801088);                  // 2,097,152 bf16
    __bf16* attn_o = (__bf16*)r4;                              // 8,388,608 bf16 (weights dead)
    __bf16* Wo_t   = (__bf16*)(ws + 27787264);                 // 4,194,304 bf16
    __bf16* c_kv_n = (__bf16*)(ws + 29884416);                 // 2,097,152 bf16
    __bf16* krope  = (__bf16*)(ws + 30932992);                 //   262,144 bf16
    // total ≈ 124.3 MB

    const int M = BATCH * SEQ;   // 4096
    dim3 blk(256);

    f32_to_bf16<<<(M * DM) / 1024, blk, 0, stream>>>(x, xb);
    transpose_w<<<dim3(3072 / 64, 2048 / 64), blk, 0, stream>>>(Wq, Wq_t, DM, NH * QKD);
    transpose_w<<<dim3(640 / 64, 2048 / 64), blk, 0, stream>>>(Wkv_a, Wkva_t, DM, KVL + QKR);
    transpose_w<<<dim3(4096 / 64, 512 / 64), blk, 0, stream>>>(Wkv_b, Wkvb_t, KVL, NH * 256);
    transpose_w<<<dim3(2048 / 64, 2048 / 64), blk, 0, stream>>>(Wo, Wo_t, NH * VD, DM);

    gemm_bf16<__bf16><<<dim3(3072 / 128, M / 128), blk, 0, stream>>>(xb, Wq_t, q_bf, DM, DM, DM, NH * QKD);
    gemm_bf16<float><<<dim3(640 / 128, M / 128), blk, 0, stream>>>(xb, Wkva_t, kv_a, DM, DM, DM, KVA_LD);

    rope_q_kernel<<<(BATCH * SEQ * NH * 32) / 256, blk, 0, stream>>>(q_bf);
    rope_k_kernel<<<(BATCH * SEQ * 32) / 256, blk, 0, stream>>>(kv_a, krope);
    rmsnorm_kernel<<<M, blk, 0, stream>>>(kv_a, kv_norm_w, c_kv_n);

    gemm_bf16<__bf16><<<dim3(4096 / 128, M / 128), blk, 0, stream>>>(c_kv_n, Wkvb_t, kv_b, KVL, KVL, KVL, NH * 256);

    build_vt<<<dim3(SEQ / 64, NH, BATCH), blk, 0, stream>>>(kv_b, Vt);

    attn_mfma<<<dim3(16, NH, BATCH), blk, 0, stream>>>(q_bf, kv_b, krope, Vt, attn_o);

    gemm_bf16<float><<<dim3(2048 / 128, M / 128), blk, 0, stream>>>(attn_o, Wo_t, out, NH * VD, NH * VD, NH * VD, DM);
}

// Round 7
// 502.475 us; speedup vs baseline: 1.2757x; 1.0088x over previous
//
#include <hip/hip_runtime.h>
#include <hip/hip_bf16.h>
#include <math.h>

#define BATCH   2
#define SEQ     2048
#define DM      2048
#define NH      16
#define QKR     64
#define QKN     128
#define KVL     512
#define VD      128
#define QKD     192     // QKN + QKR
#define KVA_LD  640     // padded row stride of kv_a (576 -> 640 for 128-tile GEMM)
#define RMS_EPS 1.1920928955078125e-07f

typedef __bf16 bf16x8 __attribute__((ext_vector_type(8)));
typedef float  f32x4  __attribute__((ext_vector_type(4)));

// ---- async global->LDS 16B copy (wave-uniform base + lane*16 dest semantics) ----
__device__ __forceinline__ void async16(const __bf16* g, __bf16* l)
{
    __builtin_amdgcn_global_load_lds(
        (__attribute__((address_space(1))) unsigned int*)g,
        (__attribute__((address_space(3))) unsigned int*)l,
        16, 0, 0);
}

// ---------------- fp32 [n] -> bf16 [n] ----------------
__global__ __launch_bounds__(256) void f32_to_bf16(const float* __restrict__ src,
                                                   __bf16* __restrict__ dst)
{
    int i = (blockIdx.x * 256 + threadIdx.x) * 4;
    float4 v = *reinterpret_cast<const float4*>(src + i);
    dst[i + 0] = (__bf16)v.x;
    dst[i + 1] = (__bf16)v.y;
    dst[i + 2] = (__bf16)v.z;
    dst[i + 3] = (__bf16)v.w;
}

// ---------------- W fp32 [K,N] -> W^T bf16 [Nout,K], zero-pad rows n>=N ----------------
__global__ __launch_bounds__(256) void transpose_w(const float* __restrict__ W,
                                                   __bf16* __restrict__ Wt,
                                                   int K, int N)
{
    __shared__ float t[64][65];
    const int n0 = blockIdx.x * 64, k0 = blockIdx.y * 64;
    const int tid = threadIdx.x;
    #pragma unroll
    for (int i = 0; i < 16; ++i) {
        int flat = i * 256 + tid;
        int kl = flat >> 6, nl = flat & 63;
        t[kl][nl] = (n0 + nl < N) ? W[(size_t)(k0 + kl) * N + n0 + nl] : 0.f;
    }
    __syncthreads();
    #pragma unroll
    for (int i = 0; i < 16; ++i) {
        int flat = i * 256 + tid;
        int nl = flat >> 6, kl = flat & 63;
        Wt[(size_t)(n0 + nl) * K + k0 + kl] = (__bf16)t[kl][nl];
    }
}

// ---------------- bf16 MFMA GEMM: C[M,N] = A[M,K] @ Bt[N,K]^T ----------------
// BK=64 (2 k-chunks of 32 per stage): halves barrier count vs BK=32.
// LDS [128][64] row stride = 128B = exact 32-bank wrap -> 16B-slot XOR swizzle
// (col8 ^ (row&7)) applied on BOTH the global source (async16 dest is linear)
// and the ds_read slot (rule: both-sides-or-neither). 2 lanes/bank after swizzle.
// Round 6: this config took total 536 -> 507 us. Keep.
template<typename OT>
__global__ __launch_bounds__(256) void gemm_bf16(const __bf16* __restrict__ A,
                                                 const __bf16* __restrict__ Bt,
                                                 OT* __restrict__ C,
                                                 int K, int lda, int ldb, int ldc)
{
    __shared__ __bf16 As[128 * 64];
    __shared__ __bf16 Bs[128 * 64];
    const int tid = threadIdx.x;
    const int lane = tid & 63, wave = tid >> 6;
    const int n = lane & 15, quad = lane >> 4;
    const int row0 = blockIdx.y * 128, col0 = blockIdx.x * 128;
    const int wm = (wave >> 1) * 64, wn = (wave & 1) * 64;

    f32x4 acc[4][4];
    #pragma unroll
    for (int mi = 0; mi < 4; ++mi)
        #pragma unroll
        for (int ni = 0; ni < 4; ++ni)
            #pragma unroll
            for (int r = 0; r < 4; ++r) acc[mi][ni][r] = 0.f;

    // staging coords: per call i (4 calls/matrix): flat = i*256+tid,
    // row = flat>>3 (+32 per call), phys col8 slot = flat&7,
    // logical col8 = phys ^ (row&7)  (inverse-swizzled source)
    const int srow = tid >> 3;
    const int scol8p = tid & 7;
    const __bf16* Ag[4]; const __bf16* Bg[4];
    #pragma unroll
    for (int i = 0; i < 4; ++i) {
        int row = srow + i * 32;
        int col8l = scol8p ^ (row & 7);
        Ag[i] = A  + (size_t)(row0 + row) * lda + col8l * 8;
        Bg[i] = Bt + (size_t)(col0 + row) * ldb + col8l * 8;
    }
    __bf16* Asd = As + tid * 8;   // + i*2048 elements per call (4KB)
    __bf16* Bsd = Bs + tid * 8;

    for (int k0 = 0; k0 < K; k0 += 64) {
        __syncthreads();
        #pragma unroll
        for (int i = 0; i < 4; ++i) {
            async16(Ag[i] + k0, Asd + i * 2048);
            async16(Bg[i] + k0, Bsd + i * 2048);
        }
        __syncthreads();

        #pragma unroll
        for (int kc = 0; kc < 2; ++kc) {
            bf16x8 af[4], bfr[4];
            #pragma unroll
            for (int mi = 0; mi < 4; ++mi) {
                int row = wm + mi * 16 + n;
                int slot = (kc * 4 + quad) ^ (row & 7);
                af[mi] = *reinterpret_cast<const bf16x8*>(&As[row * 64 + slot * 8]);
            }
            #pragma unroll
            for (int ni = 0; ni < 4; ++ni) {
                int row = wn + ni * 16 + n;
                int slot = (kc * 4 + quad) ^ (row & 7);
                bfr[ni] = *reinterpret_cast<const bf16x8*>(&Bs[row * 64 + slot * 8]);
            }
            #pragma unroll
            for (int mi = 0; mi < 4; ++mi)
                #pragma unroll
                for (int ni = 0; ni < 4; ++ni)
                    acc[mi][ni] = __builtin_amdgcn_mfma_f32_16x16x32_bf16(af[mi], bfr[ni], acc[mi][ni], 0, 0, 0);
        }
    }

    #pragma unroll
    for (int mi = 0; mi < 4; ++mi)
        #pragma unroll
        for (int r = 0; r < 4; ++r) {
            OT* cp = C + (size_t)(row0 + wm + mi * 16 + quad * 4 + r) * ldc + col0 + wn + n;
            #pragma unroll
            for (int ni = 0; ni < 4; ++ni)
                cp[ni * 16] = (OT)acc[mi][ni][r];
        }
}

// ---------------- RoPE on q (bf16, in-place), fp32 math ----------------
__global__ __launch_bounds__(256) void rope_q_kernel(__bf16* __restrict__ q)
{
    int idx = blockIdx.x * 256 + threadIdx.x;   // B*S*NH*32
    int i = idx & 31;
    int h = (idx >> 5) & 15;
    int s = (idx >> 9) & 2047;
    int b = idx >> 20;
    float t = (float)s * __expf(-(float)(2 * i) / 64.0f * 9.210340371976184f); // ln(10000)
    float c = __cosf(t), sn = __sinf(t);
    __bf16* p = q + ((size_t)(b * SEQ + s)) * (NH * QKD) + h * QKD + QKN + 2 * i;
    float x1 = (float)p[0], x2 = (float)p[1];
    p[0] = (__bf16)(x1 * c - x2 * sn);
    p[1] = (__bf16)(x2 * c + x1 * sn);
}

// ---------------- RoPE on k_rope: kv_a fp32 cols [512,576) -> bf16 krope [B,S,64] ----------------
__global__ __launch_bounds__(256) void rope_k_kernel(const float* __restrict__ kva,
                                                     __bf16* __restrict__ krope)
{
    int idx = blockIdx.x * 256 + threadIdx.x;   // B*S*32
    int i = idx & 31;
    int s = (idx >> 5) & 2047;
    int b = idx >> 16;
    float t = (float)s * __expf(-(float)(2 * i) / 64.0f * 9.210340371976184f);
    float c = __cosf(t), sn = __sinf(t);
    const float* p = kva + ((size_t)(b * SEQ + s)) * KVA_LD + KVL + 2 * i;
    float x1 = p[0], x2 = p[1];
    __bf16* o = krope + ((size_t)(b * SEQ + s)) * QKR + 2 * i;
    o[0] = (__bf16)(x1 * c - x2 * sn);
    o[1] = (__bf16)(x2 * c + x1 * sn);
}

// ---------------- RMSNorm c_kv (fp32 in, stride 640) -> bf16 out [4096,512] ----------------
__global__ __launch_bounds__(256) void rmsnorm_kernel(const float* __restrict__ kva,
                                                      const float* __restrict__ w,
                                                      __bf16* __restrict__ out)
{
    const int rid = blockIdx.x;
    const float* row = kva + (size_t)rid * KVA_LD;
    const int tid = threadIdx.x;
    float v[2];
    float ss = 0.f;
    #pragma unroll
    for (int j = 0; j < 2; ++j) {
        int d = tid + j * 256;
        v[j] = row[d];
        ss += v[j] * v[j];
    }
    #pragma unroll
    for (int off = 32; off > 0; off >>= 1) ss += __shfl_down(ss, off, 64);
    __shared__ float red[4];
    if ((tid & 63) == 0) red[tid >> 6] = ss;
    __syncthreads();
    float total = red[0] + red[1] + red[2] + red[3];
    float scale = 1.0f / sqrtf(total * (1.0f / KVL) + RMS_EPS);
    #pragma unroll
    for (int j = 0; j < 2; ++j) {
        int d = tid + j * 256;
        out[(size_t)rid * KVL + d] = (__bf16)(v[j] * scale * w[d]);
    }
}

// ---------------- build bf16 V^T : [B,H,128,S] from bf16 kv_b ----------------
__global__ __launch_bounds__(256) void build_vt(const __bf16* __restrict__ kvb,
                                                __bf16* __restrict__ Vt)
{
    __shared__ __bf16 tile[64][136];
    const int s0 = blockIdx.x * 64, h = blockIdx.y, b = blockIdx.z;
    const int t = threadIdx.x;
    #pragma unroll
    for (int i = 0; i < 4; ++i) {
        int flat = i * 256 + t;
        int sl = flat >> 4, c8 = flat & 15;
        bf16x8 v = *reinterpret_cast<const bf16x8*>(
            &kvb[((size_t)(b * SEQ + s0 + sl)) * (NH * 256) + h * 256 + 128 + c8 * 8]);
        *reinterpret_cast<bf16x8*>(&tile[sl][c8 * 8]) = v;
    }
    __syncthreads();
    #pragma unroll
    for (int j = 0; j < 32; ++j) {
        int flat = j * 256 + t;
        int d = flat >> 6, sl = flat & 63;
        Vt[((size_t)((b * NH + h) * VD + d)) * SEQ + s0 + sl] = tile[sl][d];
    }
}

// ---------------- MFMA flash attention, paired q-strips ----------------
// Round-0 structure (paired SERIAL strips, 256 thr, (256,2)) with two deltas:
//   1. single shared Ps (strips serialized; per-wave region; pre-MFMA lgkm waits
//      guarantee s=0 P-reads complete before s=1 P-writes) + LKS 216->200:
//      LDS 64512 -> 53248 B => 3 blocks/CU (12 waves/CU) vs 2 (8 waves/CU).
//   2. exact rescale-skip: when running max doesn't grow (alpha==1 bitwise),
//      skip the 4 exp + 32 Oa multiplies. Numerically identical.
// History: single-strip (256,3)=275us (VGPR 84); (256,2)+pin=210us (drain tail);
// 8-wave concurrent (512,4)=200us (VGPR 64). Paired serial = 169us. Keep structure.
#define LKS 200   // 192 + 8 pad (slot stride 25 = 1 mod 8: uniform bank spread)
#define LVS 72    // 64 + 8
#define LPS 72
__global__ __launch_bounds__(256, 2) void attn_mfma(const __bf16* __restrict__ qb,
                                                    const __bf16* __restrict__ kvb,
                                                    const __bf16* __restrict__ krope,
                                                    const __bf16* __restrict__ Vt,
                                                    __bf16* __restrict__ ob)
{
    __shared__ __bf16 Ks[64 * LKS];      // 25600 B
    __shared__ __bf16 Vs[128 * LVS];     // 18432 B
    __shared__ __bf16 Ps[4 * 16 * LPS];  //  9216 B   (total 53248 B)
    const int tid = threadIdx.x;
    const int wave = tid >> 6, lane = tid & 63;
    const int n = lane & 15, quad = lane >> 4;
    const int pair = blockIdx.x, h = blockIdx.y, b = blockIdx.z;
    const int bh = b * NH + h;
    const float scale = 0.07216878364870323f;   // 1/sqrt(192)
    int qs[2];
    qs[0] = pair; qs[1] = 31 - pair;
    const int ntmax = qs[1] + 1;

    // Q fragments for both strips (A-layout: m=n, k=quad*8+j)
    bf16x8 qfrag[2][6];
    #pragma unroll
    for (int s = 0; s < 2; ++s) {
        const int qrow = qs[s] * 64 + wave * 16 + n;
        const __bf16* qp = qb + ((size_t)(b * SEQ + qrow)) * (NH * QKD) + h * QKD + quad * 8;
        #pragma unroll
        for (int c = 0; c < 6; ++c)
            qfrag[s][c] = *reinterpret_cast<const bf16x8*>(qp + c * 32);
    }

    f32x4 Oa[2][8];
    float m_i[2][4], l_i[2][4];
    #pragma unroll
    for (int s = 0; s < 2; ++s) {
        #pragma unroll
        for (int i = 0; i < 8; ++i)
            #pragma unroll
            for (int r = 0; r < 4; ++r) Oa[s][i][r] = 0.f;
        #pragma unroll
        for (int r = 0; r < 4; ++r) { m_i[s][r] = -1e30f; l_i[s][r] = 0.f; }
    }

    // per-thread staging coordinates
    int kkey[6], kc8[6];
    #pragma unroll
    for (int i = 0; i < 6; ++i) {
        int flat = i * 256 + tid;
        kkey[i] = flat / 24; kc8[i] = flat % 24;
    }
    const int vd = tid >> 3, vc8 = tid & 7;     // flat = i*256+tid -> d = vd + i*32

    const __bf16* Vg = Vt + (size_t)bh * VD * SEQ;

    bf16x8 kpre[6], vpre[4];
    // prefetch tile 0
    {
        const int k0 = 0;
        #pragma unroll
        for (int i = 0; i < 6; ++i) {
            const __bf16* src = (kc8[i] < 16)
                ? kvb + ((size_t)(b * SEQ + k0 + kkey[i])) * (NH * 256) + h * 256 + kc8[i] * 8
                : krope + ((size_t)(b * SEQ + k0 + kkey[i])) * QKR + (kc8[i] - 16) * 8;
            kpre[i] = *reinterpret_cast<const bf16x8*>(src);
        }
        #pragma unroll
        for (int i = 0; i < 4; ++i)
            vpre[i] = *reinterpret_cast<const bf16x8*>(Vg + (size_t)(vd + i * 32) * SEQ + k0 + vc8 * 8);
    }

    for (int kt = 0; kt < ntmax; ++kt) {
        __syncthreads();   // previous iteration's compute done; Ks/Vs safe to overwrite
        #pragma unroll
        for (int i = 0; i < 6; ++i)
            *reinterpret_cast<bf16x8*>(&Ks[kkey[i] * LKS + kc8[i] * 8]) = kpre[i];
        #pragma unroll
        for (int i = 0; i < 4; ++i)
            *reinterpret_cast<bf16x8*>(&Vs[(vd + i * 32) * LVS + vc8 * 8]) = vpre[i];
        __syncthreads();

        // prefetch next tile into registers (overlaps with compute below)
        if (kt + 1 < ntmax) {
            const int k0n = (kt + 1) * 64;
            #pragma unroll
            for (int i = 0; i < 6; ++i) {
                const __bf16* src = (kc8[i] < 16)
                    ? kvb + ((size_t)(b * SEQ + k0n + kkey[i])) * (NH * 256) + h * 256 + kc8[i] * 8
                    : krope + ((size_t)(b * SEQ + k0n + kkey[i])) * QKR + (kc8[i] - 16) * 8;
                kpre[i] = *reinterpret_cast<const bf16x8*>(src);
            }
            #pragma unroll
            for (int i = 0; i < 4; ++i)
                vpre[i] = *reinterpret_cast<const bf16x8*>(Vg + (size_t)(vd + i * 32) * SEQ + k0n + vc8 * 8);
        }

        const int k0 = kt * 64;
        #pragma unroll
        for (int s = 0; s < 2; ++s) {
            if (kt > qs[s]) continue;      // strip 0 done after its diagonal

            // scores: S[16q x 64k], 4 key-subtiles x 6 d-chunks
            f32x4 sacc[4];
            #pragma unroll
            for (int t = 0; t < 4; ++t) {
                f32x4 a;
                #pragma unroll
                for (int r = 0; r < 4; ++r) a[r] = 0.f;
                #pragma unroll
                for (int c = 0; c < 6; ++c) {
                    bf16x8 kf = *reinterpret_cast<const bf16x8*>(&Ks[(t * 16 + n) * LKS + c * 32 + quad * 8]);
                    a = __builtin_amdgcn_mfma_f32_16x16x32_bf16(qfrag[s][c], kf, a, 0, 0, 0);
                }
                sacc[t] = a;
            }

            const int qg = qs[s] * 64 + wave * 16 + quad * 4;
            const bool diag = (kt == qs[s]);
            float mloc[4];
            #pragma unroll
            for (int r = 0; r < 4; ++r) mloc[r] = -1e30f;
            #pragma unroll
            for (int t = 0; t < 4; ++t) {
                int key = k0 + t * 16 + n;
                #pragma unroll
                for (int r = 0; r < 4; ++r) {
                    float sv = sacc[t][r] * scale;
                    if (diag) sv = (key <= qg + r) ? sv : -1e30f;
                    sacc[t][r] = sv;
                    mloc[r] = fmaxf(mloc[r], sv);
                }
            }
            #pragma unroll
            for (int off = 1; off < 16; off <<= 1)
                #pragma unroll
                for (int r = 0; r < 4; ++r)
                    mloc[r] = fmaxf(mloc[r], __shfl_xor(mloc[r], off, 64));

            // exact rescale-skip: alpha==1 bitwise when max didn't grow
            float mnew[4];
            #pragma unroll
            for (int r = 0; r < 4; ++r) mnew[r] = fmaxf(m_i[s][r], mloc[r]);
            int grow = __any((mnew[0] > m_i[s][0]) || (mnew[1] > m_i[s][1]) ||
                             (mnew[2] > m_i[s][2]) || (mnew[3] > m_i[s][3]));
            if (grow) {
                float alpha[4];
                #pragma unroll
                for (int r = 0; r < 4; ++r) alpha[r] = __expf(m_i[s][r] - mnew[r]);
                #pragma unroll
                for (int i = 0; i < 8; ++i)
                    #pragma unroll
                    for (int r = 0; r < 4; ++r) Oa[s][i][r] *= alpha[r];
                #pragma unroll
                for (int r = 0; r < 4; ++r) l_i[s][r] *= alpha[r];
            }
            #pragma unroll
            for (int r = 0; r < 4; ++r) m_i[s][r] = mnew[r];

            float sum[4];
            #pragma unroll
            for (int r = 0; r < 4; ++r) sum[r] = 0.f;
            #pragma unroll
            for (int t = 0; t < 4; ++t)
                #pragma unroll
                for (int r = 0; r < 4; ++r) {
                    float p = __expf(sacc[t][r] - m_i[s][r]);
                    sum[r] += p;
                    Ps[wave * 16 * LPS + (quad * 4 + r) * LPS + t * 16 + n] = (__bf16)p;
                }
            #pragma unroll
            for (int off = 1; off < 16; off <<= 1)
                #pragma unroll
                for (int r = 0; r < 4; ++r)
                    sum[r] += __shfl_xor(sum[r], off, 64);
            #pragma unroll
            for (int r = 0; r < 4; ++r) l_i[s][r] += sum[r];

            // drain P writes (per-wave region; in-wave ordering only)
            __asm__ volatile("s_waitcnt lgkmcnt(0)" ::: "memory");

            // PV: O[16q x 128vd] += P[16x64] * V[64x128]
            #pragma unroll
            for (int kc = 0; kc < 2; ++kc) {
                bf16x8 pf = *reinterpret_cast<const bf16x8*>(&Ps[wave * 16 * LPS + n * LPS + kc * 32 + quad * 8]);
                #pragma unroll
                for (int vt = 0; vt < 8; ++vt) {
                    bf16x8 vf = *reinterpret_cast<const bf16x8*>(&Vs[(vt * 16 + n) * LVS + kc * 32 + quad * 8]);
                    Oa[s][vt] = __builtin_amdgcn_mfma_f32_16x16x32_bf16(pf, vf, Oa[s][vt], 0, 0, 0);
                }
            }
        }
    }

    // epilogue: both strips
    #pragma unroll
    for (int s = 0; s < 2; ++s)
        #pragma unroll
        for (int r = 0; r < 4; ++r) {
            float inv = 1.0f / l_i[s][r];
            int row = qs[s] * 64 + wave * 16 + quad * 4 + r;
            __bf16* op = ob + ((size_t)(b * SEQ + row)) * (NH * VD) + h * VD;
            #pragma unroll
            for (int vt = 0; vt < 8; ++vt)
                op[vt * 16 + n] = (__bf16)(Oa[s][vt][r] * inv);
        }
}

extern "C" void kernel_launch(void* const* d_in, const int* in_sizes, int n_in,
                              void* d_out, int out_size, void* d_ws, size_t ws_size,
                              hipStream_t stream)
{
    const float* x         = (const float*)d_in[0];
    const float* Wq        = (const float*)d_in[1];
    const float* Wkv_a     = (const float*)d_in[2];
    const float* kv_norm_w = (const float*)d_in[3];
    const float* Wkv_b     = (const float*)d_in[4];
    const float* Wo        = (const float*)d_in[5];
    float* out = (float*)d_out;

    // workspace layout (f32-unit offsets); aliasing noted
    float* ws = (float*)d_ws;
    __bf16* q_bf   = (__bf16*)ws;                              // 12,582,912 bf16
    float*  kv_a   = ws + 6291456;                             // 4096x640 f32
    __bf16* kv_b   = (__bf16*)(ws + 8912896);                  // 16,777,216 bf16
    float*  r3     = ws + 17301504;                            // xb then Vt (alias)
    __bf16* xb     = (__bf16*)r3;                              // 8,388,608 bf16
    __bf16* Vt     = (__bf16*)r3;                              // 8,388,608 bf16
    float*  r4     = ws + 21495808;                            // weights then attn_o (alias)
    __bf16* Wq_t   = (__bf16*)r4;                              // 6,291,456 bf16
    __bf16* Wkva_t = (__bf16*)(r4 + 3145728);                  // 1,310,720 bf16
    __bf16* Wkvb_t = (__bf16*)(r4 + 3801088);                  // 2,097,152 bf16
    __bf16* attn_o = (__bf16*)r4;                              // 8,388,608 bf16 (weights dead)
    __bf16* Wo_t   = (__bf16*)(ws + 27787264);                 // 4,194,304 bf16
    __bf16* c_kv_n = (__bf16*)(ws + 29884416);                 // 2,097,152 bf16
    __bf16* krope  = (__bf16*)(ws + 30932992);                 //   262,144 bf16
    // total ≈ 124.3 MB

    const int M = BATCH * SEQ;   // 4096
    dim3 blk(256);

    f32_to_bf16<<<(M * DM) / 1024, blk, 0, stream>>>(x, xb);
    transpose_w<<<dim3(3072 / 64, 2048 / 64), blk, 0, stream>>>(Wq, Wq_t, DM, NH * QKD);
    transpose_w<<<dim3(640 / 64, 2048 / 64), blk, 0, stream>>>(Wkv_a, Wkva_t, DM, KVL + QKR);
    transpose_w<<<dim3(4096 / 64, 512 / 64), blk, 0, stream>>>(Wkv_b, Wkvb_t, KVL, NH * 256);
    transpose_w<<<dim3(2048 / 64, 2048 / 64), blk, 0, stream>>>(Wo, Wo_t, NH * VD, DM);

    gemm_bf16<__bf16><<<dim3(3072 / 128, M / 128), blk, 0, stream>>>(xb, Wq_t, q_bf, DM, DM, DM, NH * QKD);
    gemm_bf16<float><<<dim3(640 / 128, M / 128), blk, 0, stream>>>(xb, Wkva_t, kv_a, DM, DM, DM, KVA_LD);

    rope_q_kernel<<<(BATCH * SEQ * NH * 32) / 256, blk, 0, stream>>>(q_bf);
    rope_k_kernel<<<(BATCH * SEQ * 32) / 256, blk, 0, stream>>>(kv_a, krope);
    rmsnorm_kernel<<<M, blk, 0, stream>>>(kv_a, kv_norm_w, c_kv_n);

    gemm_bf16<__bf16><<<dim3(4096 / 128, M / 128), blk, 0, stream>>>(c_kv_n, Wkvb_t, kv_b, KVL, KVL, KVL, NH * 256);

    build_vt<<<dim3(SEQ / 64, NH, BATCH), blk, 0, stream>>>(kv_b, Vt);

    attn_mfma<<<dim3(16, NH, BATCH), blk, 0, stream>>>(q_bf, kv_b, krope, Vt, attn_o);

    gemm_bf16<float><<<dim3(2048 / 128, M / 128), blk, 0, stream>>>(attn_o, Wo_t, out, NH * VD, NH * VD, NH * VD, DM);
}

// Round 9
// 449.873 us; speedup vs baseline: 1.4249x; 1.1169x over previous
//
#include <hip/hip_runtime.h>
#include <hip/hip_bf16.h>
#include <math.h>

#define BATCH   2
#define SEQ     2048
#define DM      2048
#define NH      16
#define QKR     64
#define QKN     128
#define KVL     512
#define VD      128
#define QKD     192     // QKN + QKR
#define KVA_LD  640     // padded row stride of kv_a (576 -> 640 for 128-tile GEMM)
#define RMS_EPS 1.1920928955078125e-07f

typedef __bf16 bf16x8 __attribute__((ext_vector_type(8)));
typedef float  f32x4  __attribute__((ext_vector_type(4)));

// ---- async global->LDS 16B copy (wave-uniform base + lane*16 dest semantics) ----
__device__ __forceinline__ void async16(const __bf16* g, __bf16* l)
{
    __builtin_amdgcn_global_load_lds(
        (__attribute__((address_space(1))) unsigned int*)g,
        (__attribute__((address_space(3))) unsigned int*)l,
        16, 0, 0);
}

// ---- DPP row_ror lane rotate (VALU-speed cross-lane, ~4cy vs ~30cy ds_swizzle) ----
template<int CTRL>
__device__ __forceinline__ float dppf(float x)
{
    int y = __builtin_amdgcn_update_dpp(0, __builtin_bit_cast(int, x), CTRL, 0xF, 0xF, false);
    return __builtin_bit_cast(float, y);
}

// ---------------- fp32 [n] -> bf16 [n] ----------------
__global__ __launch_bounds__(256) void f32_to_bf16(const float* __restrict__ src,
                                                   __bf16* __restrict__ dst)
{
    int i = (blockIdx.x * 256 + threadIdx.x) * 4;
    float4 v = *reinterpret_cast<const float4*>(src + i);
    dst[i + 0] = (__bf16)v.x;
    dst[i + 1] = (__bf16)v.y;
    dst[i + 2] = (__bf16)v.z;
    dst[i + 3] = (__bf16)v.w;
}

// ---------------- W fp32 [K,N] -> W^T bf16 [Nout,K], zero-pad rows n>=N ----------------
__global__ __launch_bounds__(256) void transpose_w(const float* __restrict__ W,
                                                   __bf16* __restrict__ Wt,
                                                   int K, int N)
{
    __shared__ float t[64][65];
    const int n0 = blockIdx.x * 64, k0 = blockIdx.y * 64;
    const int tid = threadIdx.x;
    #pragma unroll
    for (int i = 0; i < 16; ++i) {
        int flat = i * 256 + tid;
        int kl = flat >> 6, nl = flat & 63;
        t[kl][nl] = (n0 + nl < N) ? W[(size_t)(k0 + kl) * N + n0 + nl] : 0.f;
    }
    __syncthreads();
    #pragma unroll
    for (int i = 0; i < 16; ++i) {
        int flat = i * 256 + tid;
        int nl = flat >> 6, kl = flat & 63;
        Wt[(size_t)(n0 + nl) * K + k0 + kl] = (__bf16)t[kl][nl];
    }
}

// ---------------- bf16 MFMA GEMM: C[M,N] = A[M,K] @ Bt[N,K]^T ----------------
// BK=64 + 16B-slot XOR swizzle both sides. Round 6: total 536 -> 507 us. Keep.
template<typename OT>
__global__ __launch_bounds__(256) void gemm_bf16(const __bf16* __restrict__ A,
                                                 const __bf16* __restrict__ Bt,
                                                 OT* __restrict__ C,
                                                 int K, int lda, int ldb, int ldc)
{
    __shared__ __bf16 As[128 * 64];
    __shared__ __bf16 Bs[128 * 64];
    const int tid = threadIdx.x;
    const int lane = tid & 63, wave = tid >> 6;
    const int n = lane & 15, quad = lane >> 4;
    const int row0 = blockIdx.y * 128, col0 = blockIdx.x * 128;
    const int wm = (wave >> 1) * 64, wn = (wave & 1) * 64;

    f32x4 acc[4][4];
    #pragma unroll
    for (int mi = 0; mi < 4; ++mi)
        #pragma unroll
        for (int ni = 0; ni < 4; ++ni)
            #pragma unroll
            for (int r = 0; r < 4; ++r) acc[mi][ni][r] = 0.f;

    const int srow = tid >> 3;
    const int scol8p = tid & 7;
    const __bf16* Ag[4]; const __bf16* Bg[4];
    #pragma unroll
    for (int i = 0; i < 4; ++i) {
        int row = srow + i * 32;
        int col8l = scol8p ^ (row & 7);
        Ag[i] = A  + (size_t)(row0 + row) * lda + col8l * 8;
        Bg[i] = Bt + (size_t)(col0 + row) * ldb + col8l * 8;
    }
    __bf16* Asd = As + tid * 8;   // + i*2048 elements per call (4KB)
    __bf16* Bsd = Bs + tid * 8;

    for (int k0 = 0; k0 < K; k0 += 64) {
        __syncthreads();
        #pragma unroll
        for (int i = 0; i < 4; ++i) {
            async16(Ag[i] + k0, Asd + i * 2048);
            async16(Bg[i] + k0, Bsd + i * 2048);
        }
        __syncthreads();

        #pragma unroll
        for (int kc = 0; kc < 2; ++kc) {
            bf16x8 af[4], bfr[4];
            #pragma unroll
            for (int mi = 0; mi < 4; ++mi) {
                int row = wm + mi * 16 + n;
                int slot = (kc * 4 + quad) ^ (row & 7);
                af[mi] = *reinterpret_cast<const bf16x8*>(&As[row * 64 + slot * 8]);
            }
            #pragma unroll
            for (int ni = 0; ni < 4; ++ni) {
                int row = wn + ni * 16 + n;
                int slot = (kc * 4 + quad) ^ (row & 7);
                bfr[ni] = *reinterpret_cast<const bf16x8*>(&Bs[row * 64 + slot * 8]);
            }
            #pragma unroll
            for (int mi = 0; mi < 4; ++mi)
                #pragma unroll
                for (int ni = 0; ni < 4; ++ni)
                    acc[mi][ni] = __builtin_amdgcn_mfma_f32_16x16x32_bf16(af[mi], bfr[ni], acc[mi][ni], 0, 0, 0);
        }
    }

    #pragma unroll
    for (int mi = 0; mi < 4; ++mi)
        #pragma unroll
        for (int r = 0; r < 4; ++r) {
            OT* cp = C + (size_t)(row0 + wm + mi * 16 + quad * 4 + r) * ldc + col0 + wn + n;
            #pragma unroll
            for (int ni = 0; ni < 4; ++ni)
                cp[ni * 16] = (OT)acc[mi][ni][r];
        }
}

// ---------------- RoPE on q (bf16, in-place), fp32 math ----------------
__global__ __launch_bounds__(256) void rope_q_kernel(__bf16* __restrict__ q)
{
    int idx = blockIdx.x * 256 + threadIdx.x;   // B*S*NH*32
    int i = idx & 31;
    int h = (idx >> 5) & 15;
    int s = (idx >> 9) & 2047;
    int b = idx >> 20;
    float t = (float)s * __expf(-(float)(2 * i) / 64.0f * 9.210340371976184f); // ln(10000)
    float c = __cosf(t), sn = __sinf(t);
    __bf16* p = q + ((size_t)(b * SEQ + s)) * (NH * QKD) + h * QKD + QKN + 2 * i;
    float x1 = (float)p[0], x2 = (float)p[1];
    p[0] = (__bf16)(x1 * c - x2 * sn);
    p[1] = (__bf16)(x2 * c + x1 * sn);
}

// ---------------- RoPE on k_rope: kv_a fp32 cols [512,576) -> bf16 krope [B,S,64] ----------------
__global__ __launch_bounds__(256) void rope_k_kernel(const float* __restrict__ kva,
                                                     __bf16* __restrict__ krope)
{
    int idx = blockIdx.x * 256 + threadIdx.x;   // B*S*32
    int i = idx & 31;
    int s = (idx >> 5) & 2047;
    int b = idx >> 16;
    float t = (float)s * __expf(-(float)(2 * i) / 64.0f * 9.210340371976184f);
    float c = __cosf(t), sn = __sinf(t);
    const float* p = kva + ((size_t)(b * SEQ + s)) * KVA_LD + KVL + 2 * i;
    float x1 = p[0], x2 = p[1];
    __bf16* o = krope + ((size_t)(b * SEQ + s)) * QKR + 2 * i;
    o[0] = (__bf16)(x1 * c - x2 * sn);
    o[1] = (__bf16)(x2 * c + x1 * sn);
}

// ---------------- RMSNorm c_kv (fp32 in, stride 640) -> bf16 out [4096,512] ----------------
__global__ __launch_bounds__(256) void rmsnorm_kernel(const float* __restrict__ kva,
                                                      const float* __restrict__ w,
                                                      __bf16* __restrict__ out)
{
    const int rid = blockIdx.x;
    const float* row = kva + (size_t)rid * KVA_LD;
    const int tid = threadIdx.x;
    float v[2];
    float ss = 0.f;
    #pragma unroll
    for (int j = 0; j < 2; ++j) {
        int d = tid + j * 256;
        v[j] = row[d];
        ss += v[j] * v[j];
    }
    #pragma unroll
    for (int off = 32; off > 0; off >>= 1) ss += __shfl_down(ss, off, 64);
    __shared__ float red[4];
    if ((tid & 63) == 0) red[tid >> 6] = ss;
    __syncthreads();
    float total = red[0] + red[1] + red[2] + red[3];
    float scale = 1.0f / sqrtf(total * (1.0f / KVL) + RMS_EPS);
    #pragma unroll
    for (int j = 0; j < 2; ++j) {
        int d = tid + j * 256;
        out[(size_t)rid * KVL + d] = (__bf16)(v[j] * scale * w[d]);
    }
}

// ---------------- build bf16 V^T : [B,H,128,S] from bf16 kv_b ----------------
__global__ __launch_bounds__(256) void build_vt(const __bf16* __restrict__ kvb,
                                                __bf16* __restrict__ Vt)
{
    __shared__ __bf16 tile[64][136];
    const int s0 = blockIdx.x * 64, h = blockIdx.y, b = blockIdx.z;
    const int t = threadIdx.x;
    #pragma unroll
    for (int i = 0; i < 4; ++i) {
        int flat = i * 256 + t;
        int sl = flat >> 4, c8 = flat & 15;
        bf16x8 v = *reinterpret_cast<const bf16x8*>(
            &kvb[((size_t)(b * SEQ + s0 + sl)) * (NH * 256) + h * 256 + 128 + c8 * 8]);
        *reinterpret_cast<bf16x8*>(&tile[sl][c8 * 8]) = v;
    }
    __syncthreads();
    #pragma unroll
    for (int j = 0; j < 32; ++j) {
        int flat = j * 256 + t;
        int d = flat >> 6, sl = flat & 63;
        Vt[((size_t)((b * NH + h) * VD + d)) * SEQ + s0 + sl] = tile[sl][d];
    }
}

// ---------------- MFMA flash attention, paired q-strips ----------------
// Round-7 structure (paired SERIAL strips, single Ps, rescale-skip) + two softmax
// serial-chain fixes (the stall: two 4-round shfl_xor reduces ~30cy/step on LDS pipe):
//   1. l via MFMA ones-column: Ol = mfma(P, ones, Ol), rescaled with alpha like Oa.
//      Exact same recurrence (l = l*a + rowsum(P)); kills the 4-round sum reduce.
//      Every output col identical -> every lane holds l for its rows, no broadcast.
//   2. max reduce via DPP row_ror (1,2,4,8) on VALU (~4cy/step) instead of shfl_xor.
// History: attn 170 (r0) -> 150 (r7: LDS 53KB + rescale-skip). Occ grid-limited at
// 2 blocks/CU (512 blocks); attacking serial latency, not residency.
#define LKS 200   // 192 + 8 pad (slot stride 25 = 1 mod 8: uniform bank spread)
#define LVS 72    // 64 + 8
#define LPS 72
__global__ __launch_bounds__(256, 2) void attn_mfma(const __bf16* __restrict__ qb,
                                                    const __bf16* __restrict__ kvb,
                                                    const __bf16* __restrict__ krope,
                                                    const __bf16* __restrict__ Vt,
                                                    __bf16* __restrict__ ob)
{
    __shared__ __bf16 Ks[64 * LKS];      // 25600 B
    __shared__ __bf16 Vs[128 * LVS];     // 18432 B
    __shared__ __bf16 Ps[4 * 16 * LPS];  //  9216 B   (total 53248 B)
    const int tid = threadIdx.x;
    const int wave = tid >> 6, lane = tid & 63;
    const int n = lane & 15, quad = lane >> 4;
    const int pair = blockIdx.x, h = blockIdx.y, b = blockIdx.z;
    const int bh = b * NH + h;
    const float scale = 0.07216878364870323f;   // 1/sqrt(192)
    int qs[2];
    qs[0] = pair; qs[1] = 31 - pair;
    const int ntmax = qs[1] + 1;

    const __bf16 one_bf = (__bf16)1.0f;
    const bf16x8 onesf = {one_bf, one_bf, one_bf, one_bf, one_bf, one_bf, one_bf, one_bf};

    // Q fragments for both strips (A-layout: m=n, k=quad*8+j)
    bf16x8 qfrag[2][6];
    #pragma unroll
    for (int s = 0; s < 2; ++s) {
        const int qrow = qs[s] * 64 + wave * 16 + n;
        const __bf16* qp = qb + ((size_t)(b * SEQ + qrow)) * (NH * QKD) + h * QKD + quad * 8;
        #pragma unroll
        for (int c = 0; c < 6; ++c)
            qfrag[s][c] = *reinterpret_cast<const bf16x8*>(qp + c * 32);
    }

    f32x4 Oa[2][8];
    f32x4 Ol[2];                  // l accumulator (ones-column PV output)
    float m_i[2][4];
    #pragma unroll
    for (int s = 0; s < 2; ++s) {
        #pragma unroll
        for (int i = 0; i < 8; ++i)
            #pragma unroll
            for (int r = 0; r < 4; ++r) Oa[s][i][r] = 0.f;
        #pragma unroll
        for (int r = 0; r < 4; ++r) { Ol[s][r] = 0.f; m_i[s][r] = -1e30f; }
    }

    // per-thread staging coordinates
    int kkey[6], kc8[6];
    #pragma unroll
    for (int i = 0; i < 6; ++i) {
        int flat = i * 256 + tid;
        kkey[i] = flat / 24; kc8[i] = flat % 24;
    }
    const int vd = tid >> 3, vc8 = tid & 7;     // flat = i*256+tid -> d = vd + i*32

    const __bf16* Vg = Vt + (size_t)bh * VD * SEQ;

    bf16x8 kpre[6], vpre[4];
    // prefetch tile 0
    {
        const int k0 = 0;
        #pragma unroll
        for (int i = 0; i < 6; ++i) {
            const __bf16* src = (kc8[i] < 16)
                ? kvb + ((size_t)(b * SEQ + k0 + kkey[i])) * (NH * 256) + h * 256 + kc8[i] * 8
                : krope + ((size_t)(b * SEQ + k0 + kkey[i])) * QKR + (kc8[i] - 16) * 8;
            kpre[i] = *reinterpret_cast<const bf16x8*>(src);
        }
        #pragma unroll
        for (int i = 0; i < 4; ++i)
            vpre[i] = *reinterpret_cast<const bf16x8*>(Vg + (size_t)(vd + i * 32) * SEQ + k0 + vc8 * 8);
    }

    for (int kt = 0; kt < ntmax; ++kt) {
        __syncthreads();   // previous iteration's compute done; Ks/Vs safe to overwrite
        #pragma unroll
        for (int i = 0; i < 6; ++i)
            *reinterpret_cast<bf16x8*>(&Ks[kkey[i] * LKS + kc8[i] * 8]) = kpre[i];
        #pragma unroll
        for (int i = 0; i < 4; ++i)
            *reinterpret_cast<bf16x8*>(&Vs[(vd + i * 32) * LVS + vc8 * 8]) = vpre[i];
        __syncthreads();

        // prefetch next tile into registers (overlaps with compute below)
        if (kt + 1 < ntmax) {
            const int k0n = (kt + 1) * 64;
            #pragma unroll
            for (int i = 0; i < 6; ++i) {
                const __bf16* src = (kc8[i] < 16)
                    ? kvb + ((size_t)(b * SEQ + k0n + kkey[i])) * (NH * 256) + h * 256 + kc8[i] * 8
                    : krope + ((size_t)(b * SEQ + k0n + kkey[i])) * QKR + (kc8[i] - 16) * 8;
                kpre[i] = *reinterpret_cast<const bf16x8*>(src);
            }
            #pragma unroll
            for (int i = 0; i < 4; ++i)
                vpre[i] = *reinterpret_cast<const bf16x8*>(Vg + (size_t)(vd + i * 32) * SEQ + k0n + vc8 * 8);
        }

        const int k0 = kt * 64;
        #pragma unroll
        for (int s = 0; s < 2; ++s) {
            if (kt > qs[s]) continue;      // strip 0 done after its diagonal

            // scores: S[16q x 64k], 4 key-subtiles x 6 d-chunks
            f32x4 sacc[4];
            #pragma unroll
            for (int t = 0; t < 4; ++t) {
                f32x4 a;
                #pragma unroll
                for (int r = 0; r < 4; ++r) a[r] = 0.f;
                #pragma unroll
                for (int c = 0; c < 6; ++c) {
                    bf16x8 kf = *reinterpret_cast<const bf16x8*>(&Ks[(t * 16 + n) * LKS + c * 32 + quad * 8]);
                    a = __builtin_amdgcn_mfma_f32_16x16x32_bf16(qfrag[s][c], kf, a, 0, 0, 0);
                }
                sacc[t] = a;
            }

            const int qg = qs[s] * 64 + wave * 16 + quad * 4;
            const bool diag = (kt == qs[s]);
            float mloc[4];
            #pragma unroll
            for (int r = 0; r < 4; ++r) mloc[r] = -1e30f;
            #pragma unroll
            for (int t = 0; t < 4; ++t) {
                int key = k0 + t * 16 + n;
                #pragma unroll
                for (int r = 0; r < 4; ++r) {
                    float sv = sacc[t][r] * scale;
                    if (diag) sv = (key <= qg + r) ? sv : -1e30f;
                    sacc[t][r] = sv;
                    mloc[r] = fmaxf(mloc[r], sv);
                }
            }
            // max over the 16-lane row via DPP row_ror butterfly (VALU, no LDS pipe)
            #pragma unroll
            for (int r = 0; r < 4; ++r) mloc[r] = fmaxf(mloc[r], dppf<0x121>(mloc[r]));
            #pragma unroll
            for (int r = 0; r < 4; ++r) mloc[r] = fmaxf(mloc[r], dppf<0x122>(mloc[r]));
            #pragma unroll
            for (int r = 0; r < 4; ++r) mloc[r] = fmaxf(mloc[r], dppf<0x124>(mloc[r]));
            #pragma unroll
            for (int r = 0; r < 4; ++r) mloc[r] = fmaxf(mloc[r], dppf<0x128>(mloc[r]));

            // exact rescale-skip: alpha==1 bitwise when max didn't grow
            float mnew[4];
            #pragma unroll
            for (int r = 0; r < 4; ++r) mnew[r] = fmaxf(m_i[s][r], mloc[r]);
            int grow = __any((mnew[0] > m_i[s][0]) || (mnew[1] > m_i[s][1]) ||
                             (mnew[2] > m_i[s][2]) || (mnew[3] > m_i[s][3]));
            if (grow) {
                float alpha[4];
                #pragma unroll
                for (int r = 0; r < 4; ++r) alpha[r] = __expf(m_i[s][r] - mnew[r]);
                #pragma unroll
                for (int i = 0; i < 8; ++i)
                    #pragma unroll
                    for (int r = 0; r < 4; ++r) Oa[s][i][r] *= alpha[r];
                #pragma unroll
                for (int r = 0; r < 4; ++r) Ol[s][r] *= alpha[r];
            }
            #pragma unroll
            for (int r = 0; r < 4; ++r) m_i[s][r] = mnew[r];

            #pragma unroll
            for (int t = 0; t < 4; ++t)
                #pragma unroll
                for (int r = 0; r < 4; ++r) {
                    float p = __expf(sacc[t][r] - m_i[s][r]);
                    Ps[wave * 16 * LPS + (quad * 4 + r) * LPS + t * 16 + n] = (__bf16)p;
                }

            // drain P writes (per-wave region; in-wave ordering only)
            __asm__ volatile("s_waitcnt lgkmcnt(0)" ::: "memory");

            // PV: O[16q x 128vd] += P[16x64] * V[64x128]; l += P @ ones
            #pragma unroll
            for (int kc = 0; kc < 2; ++kc) {
                bf16x8 pf = *reinterpret_cast<const bf16x8*>(&Ps[wave * 16 * LPS + n * LPS + kc * 32 + quad * 8]);
                Ol[s] = __builtin_amdgcn_mfma_f32_16x16x32_bf16(pf, onesf, Ol[s], 0, 0, 0);
                #pragma unroll
                for (int vt = 0; vt < 8; ++vt) {
                    bf16x8 vf = *reinterpret_cast<const bf16x8*>(&Vs[(vt * 16 + n) * LVS + kc * 32 + quad * 8]);
                    Oa[s][vt] = __builtin_amdgcn_mfma_f32_16x16x32_bf16(pf, vf, Oa[s][vt], 0, 0, 0);
                }
            }
        }
    }

    // epilogue: both strips
    #pragma unroll
    for (int s = 0; s < 2; ++s)
        #pragma unroll
        for (int r = 0; r < 4; ++r) {
            float inv = 1.0f / Ol[s][r];
            int row = qs[s] * 64 + wave * 16 + quad * 4 + r;
            __bf16* op = ob + ((size_t)(b * SEQ + row)) * (NH * VD) + h * VD;
            #pragma unroll
            for (int vt = 0; vt < 8; ++vt)
                op[vt * 16 + n] = (__bf16)(Oa[s][vt][r] * inv);
        }
}

extern "C" void kernel_launch(void* const* d_in, const int* in_sizes, int n_in,
                              void* d_out, int out_size, void* d_ws, size_t ws_size,
                              hipStream_t stream)
{
    const float* x         = (const float*)d_in[0];
    const float* Wq        = (const float*)d_in[1];
    const float* Wkv_a     = (const float*)d_in[2];
    const float* kv_norm_w = (const float*)d_in[3];
    const float* Wkv_b     = (const float*)d_in[4];
    const float* Wo        = (const float*)d_in[5];
    float* out = (float*)d_out;

    // workspace layout (f32-unit offsets); aliasing noted
    float* ws = (float*)d_ws;
    __bf16* q_bf   = (__bf16*)ws;                              // 12,582,912 bf16
    float*  kv_a   = ws + 6291456;                             // 4096x640 f32
    __bf16* kv_b   = (__bf16*)(ws + 8912896);                  // 16,777,216 bf16
    float*  r3     = ws + 17301504;                            // xb then Vt (alias)
    __bf16* xb     = (__bf16*)r3;                              // 8,388,608 bf16
    __bf16* Vt     = (__bf16*)r3;                              // 8,388,608 bf16
    float*  r4     = ws + 21495808;                            // weights then attn_o (alias)
    __bf16* Wq_t   = (__bf16*)r4;                              // 6,291,456 bf16
    __bf16* Wkva_t = (__bf16*)(r4 + 3145728);                  // 1,310,720 bf16
    __bf16* Wkvb_t = (__bf16*)(r4 + 3801088);                  // 2,097,152 bf16
    __bf16* attn_o = (__bf16*)r4;                              // 8,388,608 bf16 (weights dead)
    __bf16* Wo_t   = (__bf16*)(ws + 27787264);                 // 4,194,304 bf16
    __bf16* c_kv_n = (__bf16*)(ws + 29884416);                 // 2,097,152 bf16
    __bf16* krope  = (__bf16*)(ws + 30932992);                 //   262,144 bf16
    // total ≈ 124.3 MB

    const int M = BATCH * SEQ;   // 4096
    dim3 blk(256);

    f32_to_bf16<<<(M * DM) / 1024, blk, 0, stream>>>(x, xb);
    transpose_w<<<dim3(3072 / 64, 2048 / 64), blk, 0, stream>>>(Wq, Wq_t, DM, NH * QKD);
    transpose_w<<<dim3(640 / 64, 2048 / 64), blk, 0, stream>>>(Wkv_a, Wkva_t, DM, KVL + QKR);
    transpose_w<<<dim3(4096 / 64, 512 / 64), blk, 0, stream>>>(Wkv_b, Wkvb_t, KVL, NH * 256);
    transpose_w<<<dim3(2048 / 64, 2048 / 64), blk, 0, stream>>>(Wo, Wo_t, NH * VD, DM);

    gemm_bf16<__bf16><<<dim3(3072 / 128, M / 128), blk, 0, stream>>>(xb, Wq_t, q_bf, DM, DM, DM, NH * QKD);
    gemm_bf16<float><<<dim3(640 / 128, M / 128), blk, 0, stream>>>(xb, Wkva_t, kv_a, DM, DM, DM, KVA_LD);

    rope_q_kernel<<<(BATCH * SEQ * NH * 32) / 256, blk, 0, stream>>>(q_bf);
    rope_k_kernel<<<(BATCH * SEQ * 32) / 256, blk, 0, stream>>>(kv_a, krope);
    rmsnorm_kernel<<<M, blk, 0, stream>>>(kv_a, kv_norm_w, c_kv_n);

    gemm_bf16<__bf16><<<dim3(4096 / 128, M / 128), blk, 0, stream>>>(c_kv_n, Wkvb_t, kv_b, KVL, KVL, KVL, NH * 256);

    build_vt<<<dim3(SEQ / 64, NH, BATCH), blk, 0, stream>>>(kv_b, Vt);

    attn_mfma<<<dim3(16, NH, BATCH), blk, 0, stream>>>(q_bf, kv_b, krope, Vt, attn_o);

    gemm_bf16<float><<<dim3(2048 / 128, M / 128), blk, 0, stream>>>(attn_o, Wo_t, out, NH * VD, NH * VD, NH * VD, DM);
}